// Round 1
// baseline (1578.172 us; speedup 1.0000x reference)
//
#include <hip/hip_runtime.h>
#include <math.h>

#define D_IN 100
#define H    100
#define SEQL 30

typedef __attribute__((ext_vector_type(8))) short bf16x8;
typedef __attribute__((ext_vector_type(4))) float f32x4;

__device__ __forceinline__ short f2bf(float f) {
    unsigned u = __builtin_bit_cast(unsigned, f);
    unsigned r = (u + 0x7FFFu + ((u >> 16) & 1u)) >> 16;
    return (short)r;
}
__device__ __forceinline__ float bf2f(short s) {
    unsigned u = ((unsigned)(unsigned short)s) << 16;
    return __builtin_bit_cast(float, u);
}

// ---------------------------------------------------------------------------
// Wemb = emb @ W_ih^T + b_ih. W_ih transposed into LDS; each thread produces
// a float4 of 4 consecutive g columns -> b128 LDS reads.
// ---------------------------------------------------------------------------
__global__ __launch_bounds__(512) void k_wemb_t(const float* __restrict__ emb,
                                                const float* __restrict__ W_ih,
                                                const float* __restrict__ b_ih,
                                                float* __restrict__ Wemb, int V) {
    __shared__ float sWT[100 * 300];   // [d][g], 120KB
    __shared__ float sb[300];
    for (int i = threadIdx.x; i < 30000; i += 512) {
        int g = i / 100, d = i % 100;
        sWT[d * 300 + g] = W_ih[i];
    }
    for (int i = threadIdx.x; i < 300; i += 512) sb[i] = b_ih[i];
    __syncthreads();

    int v0 = blockIdx.x * 64;
    for (int t = threadIdx.x; t < 64 * 75; t += 512) {
        int vl = t / 75, gq = t % 75;
        int v = v0 + vl;
        if (v >= V) continue;
        const float4* e = (const float4*)(emb + (long)v * 100);
        float4 acc = *(const float4*)&sb[4 * gq];
#pragma unroll
        for (int d4 = 0; d4 < 25; ++d4) {
            float4 ev = e[d4];
            float4 w0 = *(const float4*)&sWT[(4 * d4 + 0) * 300 + 4 * gq];
            float4 w1 = *(const float4*)&sWT[(4 * d4 + 1) * 300 + 4 * gq];
            float4 w2 = *(const float4*)&sWT[(4 * d4 + 2) * 300 + 4 * gq];
            float4 w3 = *(const float4*)&sWT[(4 * d4 + 3) * 300 + 4 * gq];
            acc.x = fmaf(ev.x, w0.x, fmaf(ev.y, w1.x, fmaf(ev.z, w2.x, fmaf(ev.w, w3.x, acc.x))));
            acc.y = fmaf(ev.x, w0.y, fmaf(ev.y, w1.y, fmaf(ev.z, w2.y, fmaf(ev.w, w3.y, acc.y))));
            acc.z = fmaf(ev.x, w0.z, fmaf(ev.y, w1.z, fmaf(ev.z, w2.z, fmaf(ev.w, w3.z, acc.z))));
            acc.w = fmaf(ev.x, w0.w, fmaf(ev.y, w1.w, fmaf(ev.z, w2.w, fmaf(ev.w, w3.w, acc.w))));
        }
        *(float4*)(Wemb + (long)v * 300 + 4 * gq) = acc;
    }
}

// ---------------------------------------------------------------------------
// Pack W_hh^T into MFMA-B-fragment-major bf16 hi/lo tables (layout verified).
// ---------------------------------------------------------------------------
__global__ void k_bpack(const float* __restrict__ W_hh, short* __restrict__ Bhi,
                        short* __restrict__ Blo, int total /* 43008 */) {
    int t = blockIdx.x * blockDim.x + threadIdx.x;
    if (t >= total) return;
    int i    = t & 7;
    int lane = (t >> 3) & 63;
    int blk  = t >> 9;            // nt*4 + ks
    int ks = blk & 3, nt = blk >> 2;
    int np = nt * 16 + (lane & 15);
    int k  = ks * 32 + ((lane >> 4) << 3) + i;
    int g = np / 112, j = np % 112;
    float v = (j < 100 && k < 100) ? W_hh[(g * 100 + j) * 100 + k] : 0.f;
    short hi = f2bf(v);
    short lo = f2bf(v - bf2f(hi));
    Bhi[t] = hi;
    Blo[t] = lo;
}

// ---------------------------------------------------------------------------
// MFMA GRU, round 6: 4-wave (256-thread) workgroups, 16 nodes/block.
//  - wave w<3 owns column-groups {w, w+4}; wave 3 owns {3} (7 groups = 112 cols)
//  - B-hi fragments register(AGPR)-resident (96 regs max)
//  - B-lo fragments streamed from global (L2-hot 86KB table) per step,
//    ping-pong-prefetched one section ahead -> frees ~48 regs/wave
//  - per-wave unified regs ~246 <= 256  ->  TWO workgroups co-resident per CU
//    (two independent barrier domains; round 5 was register-locked to ONE
//    7-wave group/CU = 20.4% occupancy, so all waves stalled in lockstep)
//  - numerics identical to round 5 (same hi/lo split, same product order)
// ---------------------------------------------------------------------------
__global__ __launch_bounds__(256, 2) void k_gru_mfma(
        const int* __restrict__ tok, const float* __restrict__ h0,
        const float* __restrict__ Wemb, const short* __restrict__ Bhi,
        const short* __restrict__ Blo, const float* __restrict__ b_hh,
        float* __restrict__ hout, int n_nodes) {
    __shared__ short hA[2][2][16 * 136];   // [buf][hi/lo][node*136+k]

    const int tid  = threadIdx.x;
    const int w    = tid >> 6;          // 0..3
    const int lane = tid & 63;
    const int n0   = lane & 15;
    const int q    = lane >> 4;
    const int node0 = blockIdx.x * 16;
    const bool heavy = (w < 3);
    const int grp0 = w;
    const int grp1 = heavy ? (w + 4) : 3;   // wave3 dup (guarded off)

    // ---- resident B-hi fragments [gi][gate][ks] ----
    bf16x8 bh[2][3][4];
#pragma unroll
    for (int gi = 0; gi < 2; ++gi) {
        int gr = gi ? grp1 : grp0;
#pragma unroll
        for (int g = 0; g < 3; ++g)
#pragma unroll
            for (int ks = 0; ks < 4; ++ks) {
                long bo = ((long)((g * 7 + gr) * 4 + ks) * 64 + lane) * 8;
                bh[gi][g][ks] = *(const bf16x8*)&Bhi[bo];
            }
    }

    // ---- init h tables; buffer 1 zeroed so its k-pad (100..127) is 0 ----
    for (int i = tid; i < 16 * 128; i += 256) {
        int nd = i >> 7, c = i & 127;
        int row = node0 + nd; if (row >= n_nodes) row = n_nodes - 1;
        float v = (c < 100) ? h0[(long)row * 100 + c] : 0.f;
        short hi = f2bf(v);
        hA[0][0][nd * 136 + c] = hi;
        hA[0][1][nd * 136 + c] = f2bf(v - bf2f(hi));
        hA[1][0][nd * 136 + c] = 0;
        hA[1][1][nd * 136 + c] = 0;
    }

    const int j0  = grp0 * 16 + n0;           // <= 63, always valid
    const int j1  = grp1 * 16 + n0;           // may reach 111
    const bool jok1 = (j1 < 100);
    const int jc1 = jok1 ? j1 : 99;
    const float b0r = b_hh[j0], b0z = b_hh[100 + j0], b0n = b_hh[200 + j0];
    const float b1r = b_hh[jc1], b1z = b_hh[100 + jc1], b1n = b_hh[200 + jc1];

    int rows[4];
#pragma unroll
    for (int r = 0; r < 4; ++r) {
        int row = node0 + 4 * q + r;
        rows[r] = row < n_nodes ? row : n_nodes - 1;
    }
    float hp0[4], hp1[4];
#pragma unroll
    for (int r = 0; r < 4; ++r) hp0[r] = h0[(long)rows[r] * 100 + j0];
#pragma unroll
    for (int r = 0; r < 4; ++r) hp1[r] = h0[(long)rows[r] * 100 + jc1];

    __syncthreads();

    // token pipeline: tb0 = Wemb row base (element offset) for step l
    int tb0[4];
#pragma unroll
    for (int r = 0; r < 4; ++r) tb0[r] = tok[(long)rows[r] * SEQL] * 300;

    const bf16x8* blv = (const bf16x8*)Blo + lane;   // frag f at blv[f*64]

    int cur = 0;
#pragma unroll 1
    for (int l = 0; l < SEQL; ++l) {
        // 1) issue section-0 B-lo prefetch first (independent of everything)
        bf16x8 blb[2][4];
        {
            int nt = grp0;                      // s=0: gi0, g0
#pragma unroll
            for (int ks = 0; ks < 4; ++ks) blb[0][ks] = blv[(nt * 4 + ks) * 64];
        }

        // 2) issue this step's wx gathers (consumed at epilogues)
        float wx0[12], wx1[12];
#pragma unroll
        for (int g = 0; g < 3; ++g)
#pragma unroll
            for (int r = 0; r < 4; ++r)
                wx0[g * 4 + r] = Wemb[(long)tb0[r] + g * 100 + j0];
        if (heavy) {
#pragma unroll
            for (int g = 0; g < 3; ++g)
#pragma unroll
                for (int r = 0; r < 4; ++r)
                    wx1[g * 4 + r] = Wemb[(long)tb0[r] + g * 100 + jc1];
        }

        // 3) next step's token bases
        int tbn[4];
        if (l < SEQL - 1) {
#pragma unroll
            for (int r = 0; r < 4; ++r)
                tbn[r] = tok[(long)rows[r] * SEQL + l + 1] * 300;
        }

        // 4) A-fragments from current buffer
        const short* hc0 = &hA[cur][0][0];
        const short* hc1 = &hA[cur][1][0];
        bf16x8 aHi[4], aLo[4];
#pragma unroll
        for (int ks = 0; ks < 4; ++ks) {
            int off = n0 * 136 + ks * 32 + q * 8;
            aHi[ks] = *(const bf16x8*)&hc0[off];
            aLo[ks] = *(const bf16x8*)&hc1[off];
        }

        short* hn0 = &hA[cur ^ 1][0][0];
        short* hn1 = &hA[cur ^ 1][1][0];

        f32x4 acc[3];
        auto epi = [&](const float* wx, float* hp, float br, float bz,
                       float bn, int j, bool jok) {
#pragma unroll
            for (int r = 0; r < 4; ++r) {
                float pr = wx[r]     + acc[0][r] + br;
                float pz = wx[4 + r] + acc[1][r] + bz;
                float rr = __builtin_amdgcn_rcpf(1.f + __expf(-pr));
                float zz = __builtin_amdgcn_rcpf(1.f + __expf(-pz));
                float pn = wx[8 + r] + rr * (acc[2][r] + bn);
                float th = 1.f - 2.f * __builtin_amdgcn_rcpf(1.f + __expf(2.f * pn));
                float hnew = (1.f - zz) * th + zz * hp[r];
                hp[r] = hnew;
                if (jok) {
                    int off = (4 * q + r) * 136 + j;
                    short hi = f2bf(hnew);
                    hn0[off] = hi;
                    hn1[off] = f2bf(hnew - bf2f(hi));
                }
            }
        };

        // ---- gi = 0 : sections s=0..2 ----
#pragma unroll
        for (int g = 0; g < 3; ++g) acc[g] = (f32x4){0.f, 0.f, 0.f, 0.f};
#pragma unroll
        for (int g = 0; g < 3; ++g) {
            const int s = g;
            // prefetch next section's B-lo (s+1); s=2 prefetches gi1/g0
            {
                const int sn = s + 1;
                const int gin = sn / 3, gn = sn % 3;
                if (gin == 0 || heavy) {
                    int ntn = gn * 7 + (gin ? grp1 : grp0);
#pragma unroll
                    for (int ks = 0; ks < 4; ++ks)
                        blb[sn & 1][ks] = blv[(ntn * 4 + ks) * 64];
                }
            }
#pragma unroll
            for (int ks = 0; ks < 4; ++ks) {
                acc[g] = __builtin_amdgcn_mfma_f32_16x16x32_bf16(aHi[ks], bh[0][g][ks], acc[g], 0, 0, 0);
                acc[g] = __builtin_amdgcn_mfma_f32_16x16x32_bf16(aHi[ks], blb[s & 1][ks], acc[g], 0, 0, 0);
                acc[g] = __builtin_amdgcn_mfma_f32_16x16x32_bf16(aLo[ks], bh[0][g][ks], acc[g], 0, 0, 0);
            }
        }
        epi(wx0, hp0, b0r, b0z, b0n, j0, true);

        // ---- gi = 1 : sections s=3..5 (waves 0..2 only) ----
        if (heavy) {
#pragma unroll
            for (int g = 0; g < 3; ++g) acc[g] = (f32x4){0.f, 0.f, 0.f, 0.f};
#pragma unroll
            for (int g = 0; g < 3; ++g) {
                const int s = 3 + g;
                if (s < 5) {
                    const int sn = s + 1;
                    const int gn = sn % 3;
                    int ntn = gn * 7 + grp1;
#pragma unroll
                    for (int ks = 0; ks < 4; ++ks)
                        blb[sn & 1][ks] = blv[(ntn * 4 + ks) * 64];
                }
#pragma unroll
                for (int ks = 0; ks < 4; ++ks) {
                    acc[g] = __builtin_amdgcn_mfma_f32_16x16x32_bf16(aHi[ks], bh[1][g][ks], acc[g], 0, 0, 0);
                    acc[g] = __builtin_amdgcn_mfma_f32_16x16x32_bf16(aHi[ks], blb[s & 1][ks], acc[g], 0, 0, 0);
                    acc[g] = __builtin_amdgcn_mfma_f32_16x16x32_bf16(aLo[ks], bh[1][g][ks], acc[g], 0, 0, 0);
                }
            }
            epi(wx1, hp1, b1r, b1z, b1n, j1, jok1);
        }

        if (l < SEQL - 1) {
#pragma unroll
            for (int r = 0; r < 4; ++r) tb0[r] = tbn[r];
        }
        __syncthreads();
        cur ^= 1;
    }

    for (int i = tid; i < 16 * 100; i += 256) {
        int nd = i / 100, c = i % 100;
        if (node0 + nd < n_nodes)
            hout[(long)(node0 + nd) * 100 + c] =
                bf2f(hA[cur][0][nd * 136 + c]) + bf2f(hA[cur][1][nd * 136 + c]);
    }
}

// ---------------------------------------------------------------------------
// Degree (int atomics)
// ---------------------------------------------------------------------------
__global__ void k_deg(const int* __restrict__ dst, int* __restrict__ degi, int E) {
    int e = blockIdx.x * blockDim.x + threadIdx.x;
    if (e < E) atomicAdd(&degi[dst[e]], 1);
}

// ---------------------------------------------------------------------------
// Single-block scan: row_start/cursor = exclusive prefix of degi; dinv fused.
// ---------------------------------------------------------------------------
__global__ __launch_bounds__(1024) void k_scan(const int* __restrict__ degi,
                                               int* __restrict__ rs, int* __restrict__ cursor,
                                               float* __restrict__ dinv, int N, int E) {
    __shared__ int part[1024];
    int tid = threadIdx.x;
    int chunk = (N + 1023) / 1024;
    int lo = tid * chunk, hi = lo + chunk;
    if (lo > N) lo = N;
    if (hi > N) hi = N;
    int s = 0;
    for (int i = lo; i < hi; ++i) s += degi[i];
    part[tid] = s;
    __syncthreads();
    for (int off = 1; off < 1024; off <<= 1) {
        int add = (tid >= off) ? part[tid - off] : 0;
        __syncthreads();
        part[tid] += add;
        __syncthreads();
    }
    int run = (tid > 0) ? part[tid - 1] : 0;
    for (int i = lo; i < hi; ++i) {
        rs[i] = run;
        cursor[i] = run;
        int d = degi[i];
        dinv[i] = rsqrtf((float)d + 1.0f);
        run += d;
    }
    if (tid == 0) rs[N] = E;
}

// ---------------------------------------------------------------------------
// Scatter edges into CSR order (by dst)
// ---------------------------------------------------------------------------
__global__ void k_scatter(const int* __restrict__ src, const int* __restrict__ dst,
                          int* __restrict__ cursor, int* __restrict__ esrc, int E) {
    int e = blockIdx.x * blockDim.x + threadIdx.x;
    if (e >= E) return;
    int pos = atomicAdd(&cursor[dst[e]], 1);
    esrc[pos] = src[e];
}

// ---------------------------------------------------------------------------
// xw[n, 4jq..] = x[n,:] @ W[:, 4jq..] — float4 output quads, b128 LDS reads.
// ---------------------------------------------------------------------------
template <int K>
__global__ __launch_bounds__(256) void k_mm(const float* __restrict__ x,
                                            const float* __restrict__ W,
                                            float* __restrict__ out, int nquads) {
    __shared__ float sW[K * 100];
    for (int i = threadIdx.x; i < K * 100; i += 256) sW[i] = W[i];
    __syncthreads();
    int end = blockIdx.x * 2048 + 2048;
    if (end > nquads) end = nquads;
    for (int t = blockIdx.x * 2048 + threadIdx.x; t < end; t += 256) {
        int n = t / 25, jq = t % 25;
        const float4* xr = (const float4*)(x + (long)n * K);
        float4 acc = {0.f, 0.f, 0.f, 0.f};
#pragma unroll 4
        for (int d4 = 0; d4 < K / 4; ++d4) {
            float4 xv = xr[d4];
            float4 w0 = *(const float4*)&sW[(4 * d4 + 0) * 100 + 4 * jq];
            float4 w1 = *(const float4*)&sW[(4 * d4 + 1) * 100 + 4 * jq];
            float4 w2 = *(const float4*)&sW[(4 * d4 + 2) * 100 + 4 * jq];
            float4 w3 = *(const float4*)&sW[(4 * d4 + 3) * 100 + 4 * jq];
            acc.x = fmaf(xv.x, w0.x, fmaf(xv.y, w1.x, fmaf(xv.z, w2.x, fmaf(xv.w, w3.x, acc.x))));
            acc.y = fmaf(xv.x, w0.y, fmaf(xv.y, w1.y, fmaf(xv.z, w2.y, fmaf(xv.w, w3.y, acc.y))));
            acc.z = fmaf(xv.x, w0.z, fmaf(xv.y, w1.z, fmaf(xv.z, w2.z, fmaf(xv.w, w3.z, acc.z))));
            acc.w = fmaf(xv.x, w0.w, fmaf(xv.y, w1.w, fmaf(xv.z, w2.w, fmaf(xv.w, w3.w, acc.w))));
        }
        ((float4*)out)[t] = acc;
    }
}

// ---------------------------------------------------------------------------
// Conv1 finish: CSR gather (no atomics) + self term + bias, then
// xc1 = v ; xbig = relu([v, hn[idx]]).  Thread per (n, jq).
// ---------------------------------------------------------------------------
__global__ void k_conv1_fin(const int* __restrict__ rs, const int* __restrict__ esrc,
                            const float* __restrict__ xw, const float* __restrict__ dinv,
                            const float* __restrict__ b1, const float* __restrict__ hn,
                            const int* __restrict__ idx, float* __restrict__ xc1,
                            float* __restrict__ xbig, int N) {
    int t = blockIdx.x * blockDim.x + threadIdx.x;
    if (t >= N * 25) return;
    int n = t / 25, jq = t % 25;
    float dn = dinv[n];
    float4 acc = {0.f, 0.f, 0.f, 0.f};
    int e1 = rs[n + 1];
    for (int e = rs[n]; e < e1; ++e) {
        int s = esrc[e];
        float ds = dinv[s];
        float4 xs = ((const float4*)xw)[s * 25 + jq];
        acc.x = fmaf(xs.x, ds, acc.x);
        acc.y = fmaf(xs.y, ds, acc.y);
        acc.z = fmaf(xs.z, ds, acc.z);
        acc.w = fmaf(xs.w, ds, acc.w);
    }
    float4 xs = ((const float4*)xw)[t];
    float4 bq = ((const float4*)b1)[jq];
    float dn2 = dn * dn;
    float4 v;
    v.x = fmaf(acc.x, dn, fmaf(xs.x, dn2, bq.x));
    v.y = fmaf(acc.y, dn, fmaf(xs.y, dn2, bq.y));
    v.z = fmaf(acc.z, dn, fmaf(xs.z, dn2, bq.z));
    v.w = fmaf(acc.w, dn, fmaf(xs.w, dn2, bq.w));
    ((float4*)xc1)[t] = v;
    float4 rv = ((const float4*)hn)[(long)idx[n] * 25 + jq];
    float4 a = {fmaxf(v.x, 0.f), fmaxf(v.y, 0.f), fmaxf(v.z, 0.f), fmaxf(v.w, 0.f)};
    float4 b = {fmaxf(rv.x, 0.f), fmaxf(rv.y, 0.f), fmaxf(rv.z, 0.f), fmaxf(rv.w, 0.f)};
    ((float4*)xbig)[n * 50 + jq] = a;
    ((float4*)xbig)[n * 50 + 25 + jq] = b;
}

// ---------------------------------------------------------------------------
// Conv2 finish: out = [relu(agg2 + self + b2), xc1[idx]]
// ---------------------------------------------------------------------------
__global__ void k_conv2_fin(const int* __restrict__ rs, const int* __restrict__ esrc,
                            const float* __restrict__ xw, const float* __restrict__ dinv,
                            const float* __restrict__ b2, const float* __restrict__ xc1,
                            const int* __restrict__ idx, float* __restrict__ out, int N) {
    int t = blockIdx.x * blockDim.x + threadIdx.x;
    if (t >= N * 25) return;
    int n = t / 25, jq = t % 25;
    float dn = dinv[n];
    float4 acc = {0.f, 0.f, 0.f, 0.f};
    int e1 = rs[n + 1];
    for (int e = rs[n]; e < e1; ++e) {
        int s = esrc[e];
        float ds = dinv[s];
        float4 xs = ((const float4*)xw)[s * 25 + jq];
        acc.x = fmaf(xs.x, ds, acc.x);
        acc.y = fmaf(xs.y, ds, acc.y);
        acc.z = fmaf(xs.z, ds, acc.z);
        acc.w = fmaf(xs.w, ds, acc.w);
    }
    float4 xs = ((const float4*)xw)[t];
    float4 bq = ((const float4*)b2)[jq];
    float dn2 = dn * dn;
    float4 v;
    v.x = fmaxf(fmaf(acc.x, dn, fmaf(xs.x, dn2, bq.x)), 0.f);
    v.y = fmaxf(fmaf(acc.y, dn, fmaf(xs.y, dn2, bq.y)), 0.f);
    v.z = fmaxf(fmaf(acc.z, dn, fmaf(xs.z, dn2, bq.z)), 0.f);
    v.w = fmaxf(fmaf(acc.w, dn, fmaf(xs.w, dn2, bq.w)), 0.f);
    float4 rv = ((const float4*)xc1)[(long)idx[n] * 25 + jq];
    ((float4*)out)[n * 50 + jq] = v;
    ((float4*)out)[n * 50 + 25 + jq] = rv;
}

// ---------------------------------------------------------------------------
extern "C" void kernel_launch(void* const* d_in, const int* in_sizes, int n_in,
                              void* d_out, int out_size, void* d_ws, size_t ws_size,
                              hipStream_t stream) {
    const int*   feat    = (const int*)d_in[0];
    const int*   edges   = (const int*)d_in[1];
    const int*   indices = (const int*)d_in[2];
    const float* h0      = (const float*)d_in[3];
    const float* emb     = (const float*)d_in[4];
    const float* W_ih    = (const float*)d_in[5];
    const float* W_hh    = (const float*)d_in[6];
    const float* b_ih    = (const float*)d_in[7];
    const float* b_hh    = (const float*)d_in[8];
    const float* W1      = (const float*)d_in[9];
    const float* b1      = (const float*)d_in[10];
    const float* W2      = (const float*)d_in[11];
    const float* b2      = (const float*)d_in[12];
    float* out = (float*)d_out;

    const int N = in_sizes[2];
    const int E = in_sizes[1] / 2;
    const int V = in_sizes[4] / D_IN;
    const int* src = edges;
    const int* dst = edges + E;

    float* ws   = (float*)d_ws;
    float* hbuf = ws;                         // N*100
    float* Wemb = hbuf + (long)N * H;         // V*300 (reused as xw after GRU)
    float* xw   = Wemb;                       // reuse: N*100
    float* xc1  = Wemb + (long)V * 300;       // N*100
    float* xbig = xc1 + (long)N * 100;        // N*200
    float* dinv = xbig + (long)N * 200;       // N
    short* Bhi  = (short*)(dinv + N);         // 43008 bf16
    short* Blo  = Bhi + 43008;                // 43008 bf16
    int*   degi = (int*)(Blo + 43008);        // N
    int*   rs   = degi + N;                   // N+1
    int*   cursor = rs + N + 1;               // N
    int*   esrc = cursor + N;                 // E
    (void)ws_size; (void)n_in; (void)out_size;

    const int B = 256;

    hipMemsetAsync(degi, 0, (size_t)N * sizeof(int), stream);
    k_deg<<<(E + B - 1) / B, B, 0, stream>>>(dst, degi, E);
    k_scan<<<1, 1024, 0, stream>>>(degi, rs, cursor, dinv, N, E);
    k_scatter<<<(E + B - 1) / B, B, 0, stream>>>(src, dst, cursor, esrc, E);

    k_bpack<<<(43008 + B - 1) / B, B, 0, stream>>>(W_hh, Bhi, Blo, 43008);
    k_wemb_t<<<(V + 63) / 64, 512, 0, stream>>>(emb, W_ih, b_ih, Wemb, V);

    k_gru_mfma<<<(N + 15) / 16, 256, 0, stream>>>(feat, h0, Wemb, Bhi, Blo, b_hh, hbuf, N);

    {
        int nquads = N * 25;
        k_mm<100><<<(nquads + 2047) / 2048, 256, 0, stream>>>(hbuf, W1, xw, nquads);
        k_conv1_fin<<<(nquads + B - 1) / B, B, 0, stream>>>(rs, esrc, xw, dinv, b1, hbuf,
                                                            indices, xc1, xbig, N);
        k_mm<200><<<(nquads + 2047) / 2048, 256, 0, stream>>>(xbig, W2, xw, nquads);
        k_conv2_fin<<<(nquads + B - 1) / B, B, 0, stream>>>(rs, esrc, xw, dinv, b2, xc1,
                                                            indices, out, N);
    }
}

// Round 2
// 1322.381 us; speedup vs baseline: 1.1934x; 1.1934x over previous
//
#include <hip/hip_runtime.h>
#include <math.h>

#define D_IN 100
#define H    100
#define SEQL 30

typedef __attribute__((ext_vector_type(8))) short bf16x8;
typedef __attribute__((ext_vector_type(4))) float f32x4;

__device__ __forceinline__ short f2bf(float f) {
    unsigned u = __builtin_bit_cast(unsigned, f);
    unsigned r = (u + 0x7FFFu + ((u >> 16) & 1u)) >> 16;
    return (short)r;
}
__device__ __forceinline__ float bf2f(short s) {
    unsigned u = ((unsigned)(unsigned short)s) << 16;
    return __builtin_bit_cast(float, u);
}

// ---------------------------------------------------------------------------
// Wemb = emb @ W_ih^T + b_ih. W_ih transposed into LDS; each thread produces
// a float4 of 4 consecutive g columns -> b128 LDS reads.
// ---------------------------------------------------------------------------
__global__ __launch_bounds__(512) void k_wemb_t(const float* __restrict__ emb,
                                                const float* __restrict__ W_ih,
                                                const float* __restrict__ b_ih,
                                                float* __restrict__ Wemb, int V) {
    __shared__ float sWT[100 * 300];   // [d][g], 120KB
    __shared__ float sb[300];
    for (int i = threadIdx.x; i < 30000; i += 512) {
        int g = i / 100, d = i % 100;
        sWT[d * 300 + g] = W_ih[i];
    }
    for (int i = threadIdx.x; i < 300; i += 512) sb[i] = b_ih[i];
    __syncthreads();

    int v0 = blockIdx.x * 64;
    for (int t = threadIdx.x; t < 64 * 75; t += 512) {
        int vl = t / 75, gq = t % 75;
        int v = v0 + vl;
        if (v >= V) continue;
        const float4* e = (const float4*)(emb + (long)v * 100);
        float4 acc = *(const float4*)&sb[4 * gq];
#pragma unroll
        for (int d4 = 0; d4 < 25; ++d4) {
            float4 ev = e[d4];
            float4 w0 = *(const float4*)&sWT[(4 * d4 + 0) * 300 + 4 * gq];
            float4 w1 = *(const float4*)&sWT[(4 * d4 + 1) * 300 + 4 * gq];
            float4 w2 = *(const float4*)&sWT[(4 * d4 + 2) * 300 + 4 * gq];
            float4 w3 = *(const float4*)&sWT[(4 * d4 + 3) * 300 + 4 * gq];
            acc.x = fmaf(ev.x, w0.x, fmaf(ev.y, w1.x, fmaf(ev.z, w2.x, fmaf(ev.w, w3.x, acc.x))));
            acc.y = fmaf(ev.x, w0.y, fmaf(ev.y, w1.y, fmaf(ev.z, w2.y, fmaf(ev.w, w3.y, acc.y))));
            acc.z = fmaf(ev.x, w0.z, fmaf(ev.y, w1.z, fmaf(ev.z, w2.z, fmaf(ev.w, w3.z, acc.z))));
            acc.w = fmaf(ev.x, w0.w, fmaf(ev.y, w1.w, fmaf(ev.z, w2.w, fmaf(ev.w, w3.w, acc.w))));
        }
        *(float4*)(Wemb + (long)v * 300 + 4 * gq) = acc;
    }
}

// ---------------------------------------------------------------------------
// Pack W_hh^T into MFMA-B-fragment-major bf16 hi/lo tables (layout verified).
// ---------------------------------------------------------------------------
__global__ void k_bpack(const float* __restrict__ W_hh, short* __restrict__ Bhi,
                        short* __restrict__ Blo, int total /* 43008 */) {
    int t = blockIdx.x * blockDim.x + threadIdx.x;
    if (t >= total) return;
    int i    = t & 7;
    int lane = (t >> 3) & 63;
    int blk  = t >> 9;            // nt*4 + ks
    int ks = blk & 3, nt = blk >> 2;
    int np = nt * 16 + (lane & 15);
    int k  = ks * 32 + ((lane >> 4) << 3) + i;
    int g = np / 112, j = np % 112;
    float v = (j < 100 && k < 100) ? W_hh[(g * 100 + j) * 100 + k] : 0.f;
    short hi = f2bf(v);
    short lo = f2bf(v - bf2f(hi));
    Bhi[t] = hi;
    Blo[t] = lo;
}

// ---------------------------------------------------------------------------
// MFMA GRU, round 7: back to the round-0/5 structure (7 waves, wave w owns
// column tile jt=w for all 3 gates, B hi+lo register-resident, double-buffered
// h tables -> ONE barrier per step), but TWO node-tiles (32 nodes) per block:
//  - per-step busy work doubles while the fixed lockstep costs (barrier
//    drain, post-barrier lgkm wait, gather-latency residue) are amortized 2x
//  - wx for both tiles issued at the top of the step (24 live regs, same
//    budget as round-5's wxc+wxn); per-tile A-frags/acc scoped sequentially
//    so register lifetimes don't overlap (round-6 lesson: spills killed it)
// ---------------------------------------------------------------------------
__global__ __launch_bounds__(448, 2) void k_gru_mfma(
        const int* __restrict__ tok, const float* __restrict__ h0,
        const float* __restrict__ Wemb, const short* __restrict__ Bhi,
        const short* __restrict__ Blo, const float* __restrict__ b_hh,
        float* __restrict__ hout, int n_nodes) {
    __shared__ short hA[2][2][32 * 136];   // [buf][hi/lo][node*136+k], 34816B

    const int tid  = threadIdx.x;
    const int w    = tid >> 6;
    const int lane = tid & 63;
    const int n0   = lane & 15;
    const int q    = lane >> 4;
    const int node0 = blockIdx.x * 32;

    // ---- B fragments: 3 gates x 4 k-steps, hi+lo, loaded once ----
    bf16x8 bh[3][4], bl[3][4];
#pragma unroll
    for (int g = 0; g < 3; ++g)
#pragma unroll
        for (int ks = 0; ks < 4; ++ks) {
            long bo = ((long)((g * 7 + w) * 4 + ks) * 64 + lane) * 8;
            bh[g][ks] = *(const bf16x8*)&Bhi[bo];
            bl[g][ks] = *(const bf16x8*)&Blo[bo];
        }

    // ---- init h tables; buffer 1 zeroed so its k-pad (100..127) is 0 ----
    for (int i = tid; i < 32 * 128; i += 448) {
        int nd = i >> 7, c = i & 127;
        int row = node0 + nd; if (row >= n_nodes) row = n_nodes - 1;
        float v = (c < 100) ? h0[(long)row * 100 + c] : 0.f;
        short hi = f2bf(v);
        hA[0][0][nd * 136 + c] = hi;
        hA[0][1][nd * 136 + c] = f2bf(v - bf2f(hi));
        hA[1][0][nd * 136 + c] = 0;
        hA[1][1][nd * 136 + c] = 0;
    }

    const int j   = 16 * w + n0;
    const int jc  = j < 100 ? j : 99;
    const bool jok = (j < 100);
    const float bhr = b_hh[jc], bhz = b_hh[100 + jc], bhn = b_hh[200 + jc];

    int rows0[4], rows1[4];
#pragma unroll
    for (int r = 0; r < 4; ++r) {
        int row = node0 + 4 * q + r;
        rows0[r] = row < n_nodes ? row : n_nodes - 1;
        int row1 = node0 + 16 + 4 * q + r;
        rows1[r] = row1 < n_nodes ? row1 : n_nodes - 1;
    }
    float hp0[4], hp1[4];
#pragma unroll
    for (int r = 0; r < 4; ++r) hp0[r] = h0[(long)rows0[r] * 100 + jc];
#pragma unroll
    for (int r = 0; r < 4; ++r) hp1[r] = h0[(long)rows1[r] * 100 + jc];

    __syncthreads();

    // current-step Wemb row bases per tile
    int tb0[4], tb1[4];
#pragma unroll
    for (int r = 0; r < 4; ++r) tb0[r] = tok[(long)rows0[r] * SEQL] * 300;
#pragma unroll
    for (int r = 0; r < 4; ++r) tb1[r] = tok[(long)rows1[r] * SEQL] * 300;

    int cur = 0;
#pragma unroll 1
    for (int l = 0; l < SEQL; ++l) {
        // issue BOTH tiles' wx gathers first (consumed at the two epilogues;
        // tile0's cover = A-reads + 36 MFMAs, tile1's ~2x that)
        float wx0[12], wx1[12];
#pragma unroll
        for (int g = 0; g < 3; ++g)
#pragma unroll
            for (int r = 0; r < 4; ++r)
                wx0[g * 4 + r] = Wemb[(long)tb0[r] + g * 100 + jc];
#pragma unroll
        for (int g = 0; g < 3; ++g)
#pragma unroll
            for (int r = 0; r < 4; ++r)
                wx1[g * 4 + r] = Wemb[(long)tb1[r] + g * 100 + jc];

        // next step's token bases
        int tn0[4], tn1[4];
        if (l < SEQL - 1) {
#pragma unroll
            for (int r = 0; r < 4; ++r)
                tn0[r] = tok[(long)rows0[r] * SEQL + l + 1] * 300;
#pragma unroll
            for (int r = 0; r < 4; ++r)
                tn1[r] = tok[(long)rows1[r] * SEQL + l + 1] * 300;
        }

        const short* hc0 = &hA[cur][0][0];
        const short* hc1 = &hA[cur][1][0];
        short* hn0 = &hA[cur ^ 1][0][0];
        short* hn1 = &hA[cur ^ 1][1][0];

        f32x4 acc[3];
        auto epi = [&](const float* wx, float* hp, int ndo) {
#pragma unroll
            for (int r = 0; r < 4; ++r) {
                float pr = wx[r]     + acc[0][r] + bhr;
                float pz = wx[4 + r] + acc[1][r] + bhz;
                float rr = __builtin_amdgcn_rcpf(1.f + __expf(-pr));
                float zz = __builtin_amdgcn_rcpf(1.f + __expf(-pz));
                float pn = wx[8 + r] + rr * (acc[2][r] + bhn);
                float th = 1.f - 2.f * __builtin_amdgcn_rcpf(1.f + __expf(2.f * pn));
                float hnew = (1.f - zz) * th + zz * hp[r];
                hp[r] = hnew;
                if (jok) {
                    int off = (ndo + 4 * q + r) * 136 + j;
                    short hi = f2bf(hnew);
                    hn0[off] = hi;
                    hn1[off] = f2bf(hnew - bf2f(hi));
                }
            }
        };

        // ---- tile 0 (nodes node0 .. node0+15) ----
        {
            bf16x8 aHi[4], aLo[4];
#pragma unroll
            for (int ks = 0; ks < 4; ++ks) {
                int off = n0 * 136 + ks * 32 + q * 8;
                aHi[ks] = *(const bf16x8*)&hc0[off];
                aLo[ks] = *(const bf16x8*)&hc1[off];
            }
#pragma unroll
            for (int g = 0; g < 3; ++g) acc[g] = (f32x4){0.f, 0.f, 0.f, 0.f};
#pragma unroll
            for (int g = 0; g < 3; ++g)
#pragma unroll
                for (int ks = 0; ks < 4; ++ks) {
                    acc[g] = __builtin_amdgcn_mfma_f32_16x16x32_bf16(aHi[ks], bh[g][ks], acc[g], 0, 0, 0);
                    acc[g] = __builtin_amdgcn_mfma_f32_16x16x32_bf16(aHi[ks], bl[g][ks], acc[g], 0, 0, 0);
                    acc[g] = __builtin_amdgcn_mfma_f32_16x16x32_bf16(aLo[ks], bh[g][ks], acc[g], 0, 0, 0);
                }
            epi(wx0, hp0, 0);
        }

        // ---- tile 1 (nodes node0+16 .. node0+31) ----
        {
            bf16x8 aHi[4], aLo[4];
#pragma unroll
            for (int ks = 0; ks < 4; ++ks) {
                int off = (16 + n0) * 136 + ks * 32 + q * 8;
                aHi[ks] = *(const bf16x8*)&hc0[off];
                aLo[ks] = *(const bf16x8*)&hc1[off];
            }
#pragma unroll
            for (int g = 0; g < 3; ++g) acc[g] = (f32x4){0.f, 0.f, 0.f, 0.f};
#pragma unroll
            for (int g = 0; g < 3; ++g)
#pragma unroll
                for (int ks = 0; ks < 4; ++ks) {
                    acc[g] = __builtin_amdgcn_mfma_f32_16x16x32_bf16(aHi[ks], bh[g][ks], acc[g], 0, 0, 0);
                    acc[g] = __builtin_amdgcn_mfma_f32_16x16x32_bf16(aHi[ks], bl[g][ks], acc[g], 0, 0, 0);
                    acc[g] = __builtin_amdgcn_mfma_f32_16x16x32_bf16(aLo[ks], bh[g][ks], acc[g], 0, 0, 0);
                }
            epi(wx1, hp1, 16);
        }

        if (l < SEQL - 1) {
#pragma unroll
            for (int r = 0; r < 4; ++r) { tb0[r] = tn0[r]; tb1[r] = tn1[r]; }
        }
        __syncthreads();
        cur ^= 1;
    }

    for (int i = tid; i < 32 * 100; i += 448) {
        int nd = i / 100, c = i % 100;
        if (node0 + nd < n_nodes)
            hout[(long)(node0 + nd) * 100 + c] =
                bf2f(hA[cur][0][nd * 136 + c]) + bf2f(hA[cur][1][nd * 136 + c]);
    }
}

// ---------------------------------------------------------------------------
// Degree (int atomics)
// ---------------------------------------------------------------------------
__global__ void k_deg(const int* __restrict__ dst, int* __restrict__ degi, int E) {
    int e = blockIdx.x * blockDim.x + threadIdx.x;
    if (e < E) atomicAdd(&degi[dst[e]], 1);
}

// ---------------------------------------------------------------------------
// Single-block scan: row_start/cursor = exclusive prefix of degi; dinv fused.
// ---------------------------------------------------------------------------
__global__ __launch_bounds__(1024) void k_scan(const int* __restrict__ degi,
                                               int* __restrict__ rs, int* __restrict__ cursor,
                                               float* __restrict__ dinv, int N, int E) {
    __shared__ int part[1024];
    int tid = threadIdx.x;
    int chunk = (N + 1023) / 1024;
    int lo = tid * chunk, hi = lo + chunk;
    if (lo > N) lo = N;
    if (hi > N) hi = N;
    int s = 0;
    for (int i = lo; i < hi; ++i) s += degi[i];
    part[tid] = s;
    __syncthreads();
    for (int off = 1; off < 1024; off <<= 1) {
        int add = (tid >= off) ? part[tid - off] : 0;
        __syncthreads();
        part[tid] += add;
        __syncthreads();
    }
    int run = (tid > 0) ? part[tid - 1] : 0;
    for (int i = lo; i < hi; ++i) {
        rs[i] = run;
        cursor[i] = run;
        int d = degi[i];
        dinv[i] = rsqrtf((float)d + 1.0f);
        run += d;
    }
    if (tid == 0) rs[N] = E;
}

// ---------------------------------------------------------------------------
// Scatter edges into CSR order (by dst)
// ---------------------------------------------------------------------------
__global__ void k_scatter(const int* __restrict__ src, const int* __restrict__ dst,
                          int* __restrict__ cursor, int* __restrict__ esrc, int E) {
    int e = blockIdx.x * blockDim.x + threadIdx.x;
    if (e >= E) return;
    int pos = atomicAdd(&cursor[dst[e]], 1);
    esrc[pos] = src[e];
}

// ---------------------------------------------------------------------------
// xw[n, 4jq..] = x[n,:] @ W[:, 4jq..] — float4 output quads, b128 LDS reads.
// ---------------------------------------------------------------------------
template <int K>
__global__ __launch_bounds__(256) void k_mm(const float* __restrict__ x,
                                            const float* __restrict__ W,
                                            float* __restrict__ out, int nquads) {
    __shared__ float sW[K * 100];
    for (int i = threadIdx.x; i < K * 100; i += 256) sW[i] = W[i];
    __syncthreads();
    int end = blockIdx.x * 2048 + 2048;
    if (end > nquads) end = nquads;
    for (int t = blockIdx.x * 2048 + threadIdx.x; t < end; t += 256) {
        int n = t / 25, jq = t % 25;
        const float4* xr = (const float4*)(x + (long)n * K);
        float4 acc = {0.f, 0.f, 0.f, 0.f};
#pragma unroll 4
        for (int d4 = 0; d4 < K / 4; ++d4) {
            float4 xv = xr[d4];
            float4 w0 = *(const float4*)&sW[(4 * d4 + 0) * 100 + 4 * jq];
            float4 w1 = *(const float4*)&sW[(4 * d4 + 1) * 100 + 4 * jq];
            float4 w2 = *(const float4*)&sW[(4 * d4 + 2) * 100 + 4 * jq];
            float4 w3 = *(const float4*)&sW[(4 * d4 + 3) * 100 + 4 * jq];
            acc.x = fmaf(xv.x, w0.x, fmaf(xv.y, w1.x, fmaf(xv.z, w2.x, fmaf(xv.w, w3.x, acc.x))));
            acc.y = fmaf(xv.x, w0.y, fmaf(xv.y, w1.y, fmaf(xv.z, w2.y, fmaf(xv.w, w3.y, acc.y))));
            acc.z = fmaf(xv.x, w0.z, fmaf(xv.y, w1.z, fmaf(xv.z, w2.z, fmaf(xv.w, w3.z, acc.z))));
            acc.w = fmaf(xv.x, w0.w, fmaf(xv.y, w1.w, fmaf(xv.z, w2.w, fmaf(xv.w, w3.w, acc.w))));
        }
        ((float4*)out)[t] = acc;
    }
}

// ---------------------------------------------------------------------------
// Conv1 finish: CSR gather (no atomics) + self term + bias, then
// xc1 = v ; xbig = relu([v, hn[idx]]).  Thread per (n, jq).
// ---------------------------------------------------------------------------
__global__ void k_conv1_fin(const int* __restrict__ rs, const int* __restrict__ esrc,
                            const float* __restrict__ xw, const float* __restrict__ dinv,
                            const float* __restrict__ b1, const float* __restrict__ hn,
                            const int* __restrict__ idx, float* __restrict__ xc1,
                            float* __restrict__ xbig, int N) {
    int t = blockIdx.x * blockDim.x + threadIdx.x;
    if (t >= N * 25) return;
    int n = t / 25, jq = t % 25;
    float dn = dinv[n];
    float4 acc = {0.f, 0.f, 0.f, 0.f};
    int e1 = rs[n + 1];
    for (int e = rs[n]; e < e1; ++e) {
        int s = esrc[e];
        float ds = dinv[s];
        float4 xs = ((const float4*)xw)[s * 25 + jq];
        acc.x = fmaf(xs.x, ds, acc.x);
        acc.y = fmaf(xs.y, ds, acc.y);
        acc.z = fmaf(xs.z, ds, acc.z);
        acc.w = fmaf(xs.w, ds, acc.w);
    }
    float4 xs = ((const float4*)xw)[t];
    float4 bq = ((const float4*)b1)[jq];
    float dn2 = dn * dn;
    float4 v;
    v.x = fmaf(acc.x, dn, fmaf(xs.x, dn2, bq.x));
    v.y = fmaf(acc.y, dn, fmaf(xs.y, dn2, bq.y));
    v.z = fmaf(acc.z, dn, fmaf(xs.z, dn2, bq.z));
    v.w = fmaf(acc.w, dn, fmaf(xs.w, dn2, bq.w));
    ((float4*)xc1)[t] = v;
    float4 rv = ((const float4*)hn)[(long)idx[n] * 25 + jq];
    float4 a = {fmaxf(v.x, 0.f), fmaxf(v.y, 0.f), fmaxf(v.z, 0.f), fmaxf(v.w, 0.f)};
    float4 b = {fmaxf(rv.x, 0.f), fmaxf(rv.y, 0.f), fmaxf(rv.z, 0.f), fmaxf(rv.w, 0.f)};
    ((float4*)xbig)[n * 50 + jq] = a;
    ((float4*)xbig)[n * 50 + 25 + jq] = b;
}

// ---------------------------------------------------------------------------
// Conv2 finish: out = [relu(agg2 + self + b2), xc1[idx]]
// ---------------------------------------------------------------------------
__global__ void k_conv2_fin(const int* __restrict__ rs, const int* __restrict__ esrc,
                            const float* __restrict__ xw, const float* __restrict__ dinv,
                            const float* __restrict__ b2, const float* __restrict__ xc1,
                            const int* __restrict__ idx, float* __restrict__ out, int N) {
    int t = blockIdx.x * blockDim.x + threadIdx.x;
    if (t >= N * 25) return;
    int n = t / 25, jq = t % 25;
    float dn = dinv[n];
    float4 acc = {0.f, 0.f, 0.f, 0.f};
    int e1 = rs[n + 1];
    for (int e = rs[n]; e < e1; ++e) {
        int s = esrc[e];
        float ds = dinv[s];
        float4 xs = ((const float4*)xw)[s * 25 + jq];
        acc.x = fmaf(xs.x, ds, acc.x);
        acc.y = fmaf(xs.y, ds, acc.y);
        acc.z = fmaf(xs.z, ds, acc.z);
        acc.w = fmaf(xs.w, ds, acc.w);
    }
    float4 xs = ((const float4*)xw)[t];
    float4 bq = ((const float4*)b2)[jq];
    float dn2 = dn * dn;
    float4 v;
    v.x = fmaxf(fmaf(acc.x, dn, fmaf(xs.x, dn2, bq.x)), 0.f);
    v.y = fmaxf(fmaf(acc.y, dn, fmaf(xs.y, dn2, bq.y)), 0.f);
    v.z = fmaxf(fmaf(acc.z, dn, fmaf(xs.z, dn2, bq.z)), 0.f);
    v.w = fmaxf(fmaf(acc.w, dn, fmaf(xs.w, dn2, bq.w)), 0.f);
    float4 rv = ((const float4*)xc1)[(long)idx[n] * 25 + jq];
    ((float4*)out)[n * 50 + jq] = v;
    ((float4*)out)[n * 50 + 25 + jq] = rv;
}

// ---------------------------------------------------------------------------
extern "C" void kernel_launch(void* const* d_in, const int* in_sizes, int n_in,
                              void* d_out, int out_size, void* d_ws, size_t ws_size,
                              hipStream_t stream) {
    const int*   feat    = (const int*)d_in[0];
    const int*   edges   = (const int*)d_in[1];
    const int*   indices = (const int*)d_in[2];
    const float* h0      = (const float*)d_in[3];
    const float* emb     = (const float*)d_in[4];
    const float* W_ih    = (const float*)d_in[5];
    const float* W_hh    = (const float*)d_in[6];
    const float* b_ih    = (const float*)d_in[7];
    const float* b_hh    = (const float*)d_in[8];
    const float* W1      = (const float*)d_in[9];
    const float* b1      = (const float*)d_in[10];
    const float* W2      = (const float*)d_in[11];
    const float* b2      = (const float*)d_in[12];
    float* out = (float*)d_out;

    const int N = in_sizes[2];
    const int E = in_sizes[1] / 2;
    const int V = in_sizes[4] / D_IN;
    const int* src = edges;
    const int* dst = edges + E;

    float* ws   = (float*)d_ws;
    float* hbuf = ws;                         // N*100
    float* Wemb = hbuf + (long)N * H;         // V*300 (reused as xw after GRU)
    float* xw   = Wemb;                       // reuse: N*100
    float* xc1  = Wemb + (long)V * 300;       // N*100
    float* xbig = xc1 + (long)N * 100;        // N*200
    float* dinv = xbig + (long)N * 200;       // N
    short* Bhi  = (short*)(dinv + N);         // 43008 bf16
    short* Blo  = Bhi + 43008;                // 43008 bf16
    int*   degi = (int*)(Blo + 43008);        // N
    int*   rs   = degi + N;                   // N+1
    int*   cursor = rs + N + 1;               // N
    int*   esrc = cursor + N;                 // E
    (void)ws_size; (void)n_in; (void)out_size;

    const int B = 256;

    hipMemsetAsync(degi, 0, (size_t)N * sizeof(int), stream);
    k_deg<<<(E + B - 1) / B, B, 0, stream>>>(dst, degi, E);
    k_scan<<<1, 1024, 0, stream>>>(degi, rs, cursor, dinv, N, E);
    k_scatter<<<(E + B - 1) / B, B, 0, stream>>>(src, dst, cursor, esrc, E);

    k_bpack<<<(43008 + B - 1) / B, B, 0, stream>>>(W_hh, Bhi, Blo, 43008);
    k_wemb_t<<<(V + 63) / 64, 512, 0, stream>>>(emb, W_ih, b_ih, Wemb, V);

    k_gru_mfma<<<(N + 31) / 32, 448, 0, stream>>>(feat, h0, Wemb, Bhi, Blo, b_hh, hbuf, N);

    {
        int nquads = N * 25;
        k_mm<100><<<(nquads + 2047) / 2048, 256, 0, stream>>>(hbuf, W1, xw, nquads);
        k_conv1_fin<<<(nquads + B - 1) / B, B, 0, stream>>>(rs, esrc, xw, dinv, b1, hbuf,
                                                            indices, xc1, xbig, N);
        k_mm<200><<<(nquads + 2047) / 2048, 256, 0, stream>>>(xbig, W2, xw, nquads);
        k_conv2_fin<<<(nquads + B - 1) / B, B, 0, stream>>>(rs, esrc, xw, dinv, b2, xc1,
                                                            indices, out, N);
    }
}

// Round 3
// 1250.579 us; speedup vs baseline: 1.2620x; 1.0574x over previous
//
#include <hip/hip_runtime.h>
#include <math.h>

#define D_IN 100
#define H    100
#define SEQL 30

typedef __attribute__((ext_vector_type(8))) short bf16x8;
typedef __attribute__((ext_vector_type(4))) float f32x4;

__device__ __forceinline__ short f2bf(float f) {
    unsigned u = __builtin_bit_cast(unsigned, f);
    unsigned r = (u + 0x7FFFu + ((u >> 16) & 1u)) >> 16;
    return (short)r;
}
__device__ __forceinline__ float bf2f(short s) {
    unsigned u = ((unsigned)(unsigned short)s) << 16;
    return __builtin_bit_cast(float, u);
}

// ---------------------------------------------------------------------------
// Pack W_hh^T into MFMA-B-fragment-major bf16 hi/lo tables (GRU layout,
// gate-padded to 112 cols — verified, untouched).
// ---------------------------------------------------------------------------
__global__ void k_bpack(const float* __restrict__ W_hh, short* __restrict__ Bhi,
                        short* __restrict__ Blo, int total /* 43008 */) {
    int t = blockIdx.x * blockDim.x + threadIdx.x;
    if (t >= total) return;
    int i    = t & 7;
    int lane = (t >> 3) & 63;
    int blk  = t >> 9;            // nt*4 + ks
    int ks = blk & 3, nt = blk >> 2;
    int np = nt * 16 + (lane & 15);
    int k  = ks * 32 + ((lane >> 4) << 3) + i;
    int g = np / 112, j = np % 112;
    float v = (j < 100 && k < 100) ? W_hh[(g * 100 + j) * 100 + k] : 0.f;
    short hi = f2bf(v);
    short lo = f2bf(v - bf2f(hi));
    Bhi[t] = hi;
    Blo[t] = lo;
}

// ---------------------------------------------------------------------------
// Generic B-fragment pack: B[k, j] (k = reduction dim < K, j = out col < J),
// source element = trans ? W[j*ld + k] : W[k*ld + j]. Same frag layout as
// k_bpack: t = ((ct*KS + ks)*64 + lane)*8 + i; j = ct*16 + (lane&15);
// k = ks*32 + ((lane>>4)<<3) + i. Zero-padded outside K x J.
// ---------------------------------------------------------------------------
__global__ void k_pack(const float* __restrict__ W, short* __restrict__ Ph,
                       short* __restrict__ Pl, int K, int J, int ld, int trans,
                       int KS, int total) {
    int t = blockIdx.x * blockDim.x + threadIdx.x;
    if (t >= total) return;
    int i    = t & 7;
    int lane = (t >> 3) & 63;
    int blk  = t >> 9;
    int ks = blk % KS, ct = blk / KS;
    int j = ct * 16 + (lane & 15);
    int k = ks * 32 + ((lane >> 4) << 3) + i;
    float v = 0.f;
    if (j < J && k < K) v = trans ? W[(long)j * ld + k] : W[(long)k * ld + j];
    short hi = f2bf(v);
    Ph[t] = hi;
    Pl[t] = f2bf(v - bf2f(hi));
}

// ---------------------------------------------------------------------------
// Generic MFMA GEMM: out[n, j] = sum_k A[n,k]*B[k,j] (+ bias[j]).
// 64 rows/block (4 x 16-node tiles), 7 waves; wave w covers col-groups
// ct = w, w+7, ... A rows staged hi/lo bf16 in LDS (GRU-verified fragment
// layout, stride Kp+8); B frags hi/lo register-resident per group; 3-term
// hi/lo MFMA product (same order as GRU). Replaces the scalar LDS GEMMs
// (k_wemb_t / k_mm), whose float4-quad LDS reads were ~8-way bank-conflicted.
// ---------------------------------------------------------------------------
template <int KS>
__global__ __launch_bounds__(448) void k_gemm(
        const float* __restrict__ A, int K, int nrows,
        const short* __restrict__ Bh, const short* __restrict__ Bl,
        const float* __restrict__ bias, float* __restrict__ out, int ldo,
        int J, int CT) {
    constexpr int Kp  = KS * 32;
    constexpr int STR = Kp + 8;                 // shorts per staged row
    __shared__ short sA[2][64 * STR];           // [hi/lo][row*STR + k]

    const int tid  = threadIdx.x;
    const int w    = tid >> 6;
    const int lane = tid & 63;
    const int n0   = lane & 15;
    const int q    = lane >> 4;
    const int row0 = blockIdx.x * 64;

    // ---- stage A rows as bf16 hi/lo (coalesced: consecutive tid -> k) ----
    for (int idx = tid; idx < 64 * Kp; idx += 448) {
        int nd = idx / Kp, c = idx % Kp;
        int r = row0 + nd; if (r >= nrows) r = nrows - 1;
        float v = (c < K) ? A[(long)r * K + c] : 0.f;
        short hi = f2bf(v);
        sA[0][nd * STR + c] = hi;
        sA[1][nd * STR + c] = f2bf(v - bf2f(hi));
    }
    __syncthreads();

    for (int ct = w; ct < CT; ct += 7) {
        bf16x8 bh[KS], bl[KS];
#pragma unroll
        for (int ks = 0; ks < KS; ++ks) {
            long bo = ((long)(ct * KS + ks) * 64 + lane) * 8;
            bh[ks] = *(const bf16x8*)&Bh[bo];
            bl[ks] = *(const bf16x8*)&Bl[bo];
        }
        const int j = ct * 16 + n0;
        const bool jv = (j < J);
        const float bv = (bias != nullptr && jv) ? bias[j] : 0.f;

#pragma unroll
        for (int t = 0; t < 4; ++t) {
            f32x4 acc = (f32x4){0.f, 0.f, 0.f, 0.f};
#pragma unroll
            for (int ks = 0; ks < KS; ++ks) {
                int off = (t * 16 + n0) * STR + ks * 32 + q * 8;
                bf16x8 aHi = *(const bf16x8*)&sA[0][off];
                bf16x8 aLo = *(const bf16x8*)&sA[1][off];
                acc = __builtin_amdgcn_mfma_f32_16x16x32_bf16(aHi, bh[ks], acc, 0, 0, 0);
                acc = __builtin_amdgcn_mfma_f32_16x16x32_bf16(aHi, bl[ks], acc, 0, 0, 0);
                acc = __builtin_amdgcn_mfma_f32_16x16x32_bf16(aLo, bh[ks], acc, 0, 0, 0);
            }
            if (jv) {
#pragma unroll
                for (int r = 0; r < 4; ++r) {
                    int row = row0 + t * 16 + 4 * q + r;
                    if (row < nrows) out[(long)row * ldo + j] = acc[r] + bv;
                }
            }
        }
    }
}

// ---------------------------------------------------------------------------
// MFMA GRU (round 7 structure, unchanged): 7 waves, wave w owns column tile
// jt=w, B hi+lo register-resident, double-buffered h tables, ONE barrier per
// step, TWO 16-node tiles per block.
// ---------------------------------------------------------------------------
__global__ __launch_bounds__(448, 2) void k_gru_mfma(
        const int* __restrict__ tok, const float* __restrict__ h0,
        const float* __restrict__ Wemb, const short* __restrict__ Bhi,
        const short* __restrict__ Blo, const float* __restrict__ b_hh,
        float* __restrict__ hout, int n_nodes) {
    __shared__ short hA[2][2][32 * 136];   // [buf][hi/lo][node*136+k], 34816B

    const int tid  = threadIdx.x;
    const int w    = tid >> 6;
    const int lane = tid & 63;
    const int n0   = lane & 15;
    const int q    = lane >> 4;
    const int node0 = blockIdx.x * 32;

    // ---- B fragments: 3 gates x 4 k-steps, hi+lo, loaded once ----
    bf16x8 bh[3][4], bl[3][4];
#pragma unroll
    for (int g = 0; g < 3; ++g)
#pragma unroll
        for (int ks = 0; ks < 4; ++ks) {
            long bo = ((long)((g * 7 + w) * 4 + ks) * 64 + lane) * 8;
            bh[g][ks] = *(const bf16x8*)&Bhi[bo];
            bl[g][ks] = *(const bf16x8*)&Blo[bo];
        }

    // ---- init h tables; buffer 1 zeroed so its k-pad (100..127) is 0 ----
    for (int i = tid; i < 32 * 128; i += 448) {
        int nd = i >> 7, c = i & 127;
        int row = node0 + nd; if (row >= n_nodes) row = n_nodes - 1;
        float v = (c < 100) ? h0[(long)row * 100 + c] : 0.f;
        short hi = f2bf(v);
        hA[0][0][nd * 136 + c] = hi;
        hA[0][1][nd * 136 + c] = f2bf(v - bf2f(hi));
        hA[1][0][nd * 136 + c] = 0;
        hA[1][1][nd * 136 + c] = 0;
    }

    const int j   = 16 * w + n0;
    const int jc  = j < 100 ? j : 99;
    const bool jok = (j < 100);
    const float bhr = b_hh[jc], bhz = b_hh[100 + jc], bhn = b_hh[200 + jc];

    int rows0[4], rows1[4];
#pragma unroll
    for (int r = 0; r < 4; ++r) {
        int row = node0 + 4 * q + r;
        rows0[r] = row < n_nodes ? row : n_nodes - 1;
        int row1 = node0 + 16 + 4 * q + r;
        rows1[r] = row1 < n_nodes ? row1 : n_nodes - 1;
    }
    float hp0[4], hp1[4];
#pragma unroll
    for (int r = 0; r < 4; ++r) hp0[r] = h0[(long)rows0[r] * 100 + jc];
#pragma unroll
    for (int r = 0; r < 4; ++r) hp1[r] = h0[(long)rows1[r] * 100 + jc];

    __syncthreads();

    // current-step Wemb row bases per tile
    int tb0[4], tb1[4];
#pragma unroll
    for (int r = 0; r < 4; ++r) tb0[r] = tok[(long)rows0[r] * SEQL] * 300;
#pragma unroll
    for (int r = 0; r < 4; ++r) tb1[r] = tok[(long)rows1[r] * SEQL] * 300;

    int cur = 0;
#pragma unroll 1
    for (int l = 0; l < SEQL; ++l) {
        // issue BOTH tiles' wx gathers first (consumed at the two epilogues)
        float wx0[12], wx1[12];
#pragma unroll
        for (int g = 0; g < 3; ++g)
#pragma unroll
            for (int r = 0; r < 4; ++r)
                wx0[g * 4 + r] = Wemb[(long)tb0[r] + g * 100 + jc];
#pragma unroll
        for (int g = 0; g < 3; ++g)
#pragma unroll
            for (int r = 0; r < 4; ++r)
                wx1[g * 4 + r] = Wemb[(long)tb1[r] + g * 100 + jc];

        // next step's token bases
        int tn0[4], tn1[4];
        if (l < SEQL - 1) {
#pragma unroll
            for (int r = 0; r < 4; ++r)
                tn0[r] = tok[(long)rows0[r] * SEQL + l + 1] * 300;
#pragma unroll
            for (int r = 0; r < 4; ++r)
                tn1[r] = tok[(long)rows1[r] * SEQL + l + 1] * 300;
        }

        const short* hc0 = &hA[cur][0][0];
        const short* hc1 = &hA[cur][1][0];
        short* hn0 = &hA[cur ^ 1][0][0];
        short* hn1 = &hA[cur ^ 1][1][0];

        f32x4 acc[3];
        auto epi = [&](const float* wx, float* hp, int ndo) {
#pragma unroll
            for (int r = 0; r < 4; ++r) {
                float pr = wx[r]     + acc[0][r] + bhr;
                float pz = wx[4 + r] + acc[1][r] + bhz;
                float rr = __builtin_amdgcn_rcpf(1.f + __expf(-pr));
                float zz = __builtin_amdgcn_rcpf(1.f + __expf(-pz));
                float pn = wx[8 + r] + rr * (acc[2][r] + bhn);
                float th = 1.f - 2.f * __builtin_amdgcn_rcpf(1.f + __expf(2.f * pn));
                float hnew = (1.f - zz) * th + zz * hp[r];
                hp[r] = hnew;
                if (jok) {
                    int off = (ndo + 4 * q + r) * 136 + j;
                    short hi = f2bf(hnew);
                    hn0[off] = hi;
                    hn1[off] = f2bf(hnew - bf2f(hi));
                }
            }
        };

        // ---- tile 0 (nodes node0 .. node0+15) ----
        {
            bf16x8 aHi[4], aLo[4];
#pragma unroll
            for (int ks = 0; ks < 4; ++ks) {
                int off = n0 * 136 + ks * 32 + q * 8;
                aHi[ks] = *(const bf16x8*)&hc0[off];
                aLo[ks] = *(const bf16x8*)&hc1[off];
            }
#pragma unroll
            for (int g = 0; g < 3; ++g) acc[g] = (f32x4){0.f, 0.f, 0.f, 0.f};
#pragma unroll
            for (int g = 0; g < 3; ++g)
#pragma unroll
                for (int ks = 0; ks < 4; ++ks) {
                    acc[g] = __builtin_amdgcn_mfma_f32_16x16x32_bf16(aHi[ks], bh[g][ks], acc[g], 0, 0, 0);
                    acc[g] = __builtin_amdgcn_mfma_f32_16x16x32_bf16(aHi[ks], bl[g][ks], acc[g], 0, 0, 0);
                    acc[g] = __builtin_amdgcn_mfma_f32_16x16x32_bf16(aLo[ks], bh[g][ks], acc[g], 0, 0, 0);
                }
            epi(wx0, hp0, 0);
        }

        // ---- tile 1 (nodes node0+16 .. node0+31) ----
        {
            bf16x8 aHi[4], aLo[4];
#pragma unroll
            for (int ks = 0; ks < 4; ++ks) {
                int off = (16 + n0) * 136 + ks * 32 + q * 8;
                aHi[ks] = *(const bf16x8*)&hc0[off];
                aLo[ks] = *(const bf16x8*)&hc1[off];
            }
#pragma unroll
            for (int g = 0; g < 3; ++g) acc[g] = (f32x4){0.f, 0.f, 0.f, 0.f};
#pragma unroll
            for (int g = 0; g < 3; ++g)
#pragma unroll
                for (int ks = 0; ks < 4; ++ks) {
                    acc[g] = __builtin_amdgcn_mfma_f32_16x16x32_bf16(aHi[ks], bh[g][ks], acc[g], 0, 0, 0);
                    acc[g] = __builtin_amdgcn_mfma_f32_16x16x32_bf16(aHi[ks], bl[g][ks], acc[g], 0, 0, 0);
                    acc[g] = __builtin_amdgcn_mfma_f32_16x16x32_bf16(aLo[ks], bh[g][ks], acc[g], 0, 0, 0);
                }
            epi(wx1, hp1, 16);
        }

        if (l < SEQL - 1) {
#pragma unroll
            for (int r = 0; r < 4; ++r) { tb0[r] = tn0[r]; tb1[r] = tn1[r]; }
        }
        __syncthreads();
        cur ^= 1;
    }

    for (int i = tid; i < 32 * 100; i += 448) {
        int nd = i / 100, c = i % 100;
        if (node0 + nd < n_nodes)
            hout[(long)(node0 + nd) * 100 + c] =
                bf2f(hA[cur][0][nd * 136 + c]) + bf2f(hA[cur][1][nd * 136 + c]);
    }
}

// ---------------------------------------------------------------------------
// Degree (int atomics)
// ---------------------------------------------------------------------------
__global__ void k_deg(const int* __restrict__ dst, int* __restrict__ degi, int E) {
    int e = blockIdx.x * blockDim.x + threadIdx.x;
    if (e < E) atomicAdd(&degi[dst[e]], 1);
}

// ---------------------------------------------------------------------------
// Single-block scan: row_start/cursor = exclusive prefix of degi; dinv fused.
// ---------------------------------------------------------------------------
__global__ __launch_bounds__(1024) void k_scan(const int* __restrict__ degi,
                                               int* __restrict__ rs, int* __restrict__ cursor,
                                               float* __restrict__ dinv, int N, int E) {
    __shared__ int part[1024];
    int tid = threadIdx.x;
    int chunk = (N + 1023) / 1024;
    int lo = tid * chunk, hi = lo + chunk;
    if (lo > N) lo = N;
    if (hi > N) hi = N;
    int s = 0;
    for (int i = lo; i < hi; ++i) s += degi[i];
    part[tid] = s;
    __syncthreads();
    for (int off = 1; off < 1024; off <<= 1) {
        int add = (tid >= off) ? part[tid - off] : 0;
        __syncthreads();
        part[tid] += add;
        __syncthreads();
    }
    int run = (tid > 0) ? part[tid - 1] : 0;
    for (int i = lo; i < hi; ++i) {
        rs[i] = run;
        cursor[i] = run;
        int d = degi[i];
        dinv[i] = rsqrtf((float)d + 1.0f);
        run += d;
    }
    if (tid == 0) rs[N] = E;
}

// ---------------------------------------------------------------------------
// Scatter edges into CSR order (by dst)
// ---------------------------------------------------------------------------
__global__ void k_scatter(const int* __restrict__ src, const int* __restrict__ dst,
                          int* __restrict__ cursor, int* __restrict__ esrc, int E) {
    int e = blockIdx.x * blockDim.x + threadIdx.x;
    if (e >= E) return;
    int pos = atomicAdd(&cursor[dst[e]], 1);
    esrc[pos] = src[e];
}

// ---------------------------------------------------------------------------
// Conv1 finish: CSR gather (no atomics) + self term + bias, then
// xc1 = v ; xbig = relu([v, hn[idx]]).  Thread per (n, jq).
// ---------------------------------------------------------------------------
__global__ void k_conv1_fin(const int* __restrict__ rs, const int* __restrict__ esrc,
                            const float* __restrict__ xw, const float* __restrict__ dinv,
                            const float* __restrict__ b1, const float* __restrict__ hn,
                            const int* __restrict__ idx, float* __restrict__ xc1,
                            float* __restrict__ xbig, int N) {
    int t = blockIdx.x * blockDim.x + threadIdx.x;
    if (t >= N * 25) return;
    int n = t / 25, jq = t % 25;
    float dn = dinv[n];
    float4 acc = {0.f, 0.f, 0.f, 0.f};
    int e1 = rs[n + 1];
    for (int e = rs[n]; e < e1; ++e) {
        int s = esrc[e];
        float ds = dinv[s];
        float4 xs = ((const float4*)xw)[s * 25 + jq];
        acc.x = fmaf(xs.x, ds, acc.x);
        acc.y = fmaf(xs.y, ds, acc.y);
        acc.z = fmaf(xs.z, ds, acc.z);
        acc.w = fmaf(xs.w, ds, acc.w);
    }
    float4 xs = ((const float4*)xw)[t];
    float4 bq = ((const float4*)b1)[jq];
    float dn2 = dn * dn;
    float4 v;
    v.x = fmaf(acc.x, dn, fmaf(xs.x, dn2, bq.x));
    v.y = fmaf(acc.y, dn, fmaf(xs.y, dn2, bq.y));
    v.z = fmaf(acc.z, dn, fmaf(xs.z, dn2, bq.z));
    v.w = fmaf(acc.w, dn, fmaf(xs.w, dn2, bq.w));
    ((float4*)xc1)[t] = v;
    float4 rv = ((const float4*)hn)[(long)idx[n] * 25 + jq];
    float4 a = {fmaxf(v.x, 0.f), fmaxf(v.y, 0.f), fmaxf(v.z, 0.f), fmaxf(v.w, 0.f)};
    float4 b = {fmaxf(rv.x, 0.f), fmaxf(rv.y, 0.f), fmaxf(rv.z, 0.f), fmaxf(rv.w, 0.f)};
    ((float4*)xbig)[n * 50 + jq] = a;
    ((float4*)xbig)[n * 50 + 25 + jq] = b;
}

// ---------------------------------------------------------------------------
// Conv2 finish: out = [relu(agg2 + self + b2), xc1[idx]]
// ---------------------------------------------------------------------------
__global__ void k_conv2_fin(const int* __restrict__ rs, const int* __restrict__ esrc,
                            const float* __restrict__ xw, const float* __restrict__ dinv,
                            const float* __restrict__ b2, const float* __restrict__ xc1,
                            const int* __restrict__ idx, float* __restrict__ out, int N) {
    int t = blockIdx.x * blockDim.x + threadIdx.x;
    if (t >= N * 25) return;
    int n = t / 25, jq = t % 25;
    float dn = dinv[n];
    float4 acc = {0.f, 0.f, 0.f, 0.f};
    int e1 = rs[n + 1];
    for (int e = rs[n]; e < e1; ++e) {
        int s = esrc[e];
        float ds = dinv[s];
        float4 xs = ((const float4*)xw)[s * 25 + jq];
        acc.x = fmaf(xs.x, ds, acc.x);
        acc.y = fmaf(xs.y, ds, acc.y);
        acc.z = fmaf(xs.z, ds, acc.z);
        acc.w = fmaf(xs.w, ds, acc.w);
    }
    float4 xs = ((const float4*)xw)[t];
    float4 bq = ((const float4*)b2)[jq];
    float dn2 = dn * dn;
    float4 v;
    v.x = fmaxf(fmaf(acc.x, dn, fmaf(xs.x, dn2, bq.x)), 0.f);
    v.y = fmaxf(fmaf(acc.y, dn, fmaf(xs.y, dn2, bq.y)), 0.f);
    v.z = fmaxf(fmaf(acc.z, dn, fmaf(xs.z, dn2, bq.z)), 0.f);
    v.w = fmaxf(fmaf(acc.w, dn, fmaf(xs.w, dn2, bq.w)), 0.f);
    float4 rv = ((const float4*)xc1)[(long)idx[n] * 25 + jq];
    ((float4*)out)[n * 50 + jq] = v;
    ((float4*)out)[n * 50 + 25 + jq] = rv;
}

// ---------------------------------------------------------------------------
extern "C" void kernel_launch(void* const* d_in, const int* in_sizes, int n_in,
                              void* d_out, int out_size, void* d_ws, size_t ws_size,
                              hipStream_t stream) {
    const int*   feat    = (const int*)d_in[0];
    const int*   edges   = (const int*)d_in[1];
    const int*   indices = (const int*)d_in[2];
    const float* h0      = (const float*)d_in[3];
    const float* emb     = (const float*)d_in[4];
    const float* W_ih    = (const float*)d_in[5];
    const float* W_hh    = (const float*)d_in[6];
    const float* b_ih    = (const float*)d_in[7];
    const float* b_hh    = (const float*)d_in[8];
    const float* W1      = (const float*)d_in[9];
    const float* b1      = (const float*)d_in[10];
    const float* W2      = (const float*)d_in[11];
    const float* b2      = (const float*)d_in[12];
    float* out = (float*)d_out;

    const int N = in_sizes[2];
    const int E = in_sizes[1] / 2;
    const int V = in_sizes[4] / D_IN;
    const int* src = edges;
    const int* dst = edges + E;

    float* ws   = (float*)d_ws;
    float* hbuf = ws;                         // N*100
    float* Wemb = hbuf + (long)N * H;         // V*300 (reused as xw after GRU)
    float* xw   = Wemb;                       // reuse: N*100
    float* xc1  = Wemb + (long)V * 300;       // N*100
    float* xbig = xc1 + (long)N * 100;        // N*200
    float* dinv = xbig + (long)N * 200;       // N
    short* Bhi  = (short*)(dinv + N);         // 43008 bf16 (GRU W_hh)
    short* Blo  = Bhi + 43008;                // 43008
    short* PihH = Blo + 43008;                // 38912 (W_ih: CT=19, KS=4)
    short* PihL = PihH + 38912;               // 38912
    short* P1H  = PihL + 38912;               // 14336 (W1: CT=7, KS=4)
    short* P1L  = P1H + 14336;                // 14336
    short* P2H  = P1L + 14336;                // 25088 (W2: CT=7, KS=7)
    short* P2L  = P2H + 25088;                // 25088
    int*   degi = (int*)(P2L + 25088);        // N  (offset stays 4B-aligned)
    int*   rs   = degi + N;                   // N+1
    int*   cursor = rs + N + 1;               // N
    int*   esrc = cursor + N;                 // E
    (void)ws_size; (void)n_in; (void)out_size;

    const int B = 256;

    hipMemsetAsync(degi, 0, (size_t)N * sizeof(int), stream);
    k_deg<<<(E + B - 1) / B, B, 0, stream>>>(dst, degi, E);
    k_scan<<<1, 1024, 0, stream>>>(degi, rs, cursor, dinv, N, E);
    k_scatter<<<(E + B - 1) / B, B, 0, stream>>>(src, dst, cursor, esrc, E);

    k_bpack<<<(43008 + B - 1) / B, B, 0, stream>>>(W_hh, Bhi, Blo, 43008);
    // W_ih: B[k,j] = W_ih[j*100+k]  (j<300 out cols, k<100)
    k_pack<<<(38912 + B - 1) / B, B, 0, stream>>>(W_ih, PihH, PihL, 100, 300, 100, 1, 4, 38912);
    // W1: B[k,j] = W1[k*100+j]
    k_pack<<<(14336 + B - 1) / B, B, 0, stream>>>(W1, P1H, P1L, 100, 100, 100, 0, 4, 14336);
    // W2: B[k,j] = W2[k*100+j]
    k_pack<<<(25088 + B - 1) / B, B, 0, stream>>>(W2, P2H, P2L, 200, 100, 100, 0, 7, 25088);

    // Wemb = emb @ W_ih^T + b_ih   [V x 300]
    k_gemm<4><<<(V + 63) / 64, 448, 0, stream>>>(emb, 100, V, PihH, PihL, b_ih,
                                                 Wemb, 300, 300, 19);

    k_gru_mfma<<<(N + 31) / 32, 448, 0, stream>>>(feat, h0, Wemb, Bhi, Blo, b_hh, hbuf, N);

    {
        // xw = hbuf @ W1   [N x 100]
        k_gemm<4><<<(N + 63) / 64, 448, 0, stream>>>(hbuf, 100, N, P1H, P1L, nullptr,
                                                     xw, 100, 100, 7);
        int nquads = N * 25;
        k_conv1_fin<<<(nquads + B - 1) / B, B, 0, stream>>>(rs, esrc, xw, dinv, b1, hbuf,
                                                            indices, xc1, xbig, N);
        // xw = xbig @ W2   [N x 100]
        k_gemm<7><<<(N + 63) / 64, 448, 0, stream>>>(xbig, 200, N, P2H, P2L, nullptr,
                                                     xw, 100, 100, 7);
        k_conv2_fin<<<(nquads + B - 1) / B, B, 0, stream>>>(rs, esrc, xw, dinv, b2, xc1,
                                                            indices, out, N);
    }
}

// Round 4
// 1000.074 us; speedup vs baseline: 1.5781x; 1.2505x over previous
//
#include <hip/hip_runtime.h>
#include <math.h>

#define D_IN 100
#define H    100
#define SEQL 30

typedef __attribute__((ext_vector_type(8))) short bf16x8;
typedef __attribute__((ext_vector_type(4))) float f32x4;

__device__ __forceinline__ short f2bf(float f) {
    unsigned u = __builtin_bit_cast(unsigned, f);
    unsigned r = (u + 0x7FFFu + ((u >> 16) & 1u)) >> 16;
    return (short)r;
}
__device__ __forceinline__ float bf2f(short s) {
    unsigned u = ((unsigned)(unsigned short)s) << 16;
    return __builtin_bit_cast(float, u);
}

// ---------------------------------------------------------------------------
// Pack W_hh^T into MFMA-B-fragment-major bf16 hi/lo tables (GRU layout,
// gate-padded to 112 cols — verified, untouched).
// ---------------------------------------------------------------------------
__global__ void k_bpack(const float* __restrict__ W_hh, short* __restrict__ Bhi,
                        short* __restrict__ Blo, int total /* 43008 */) {
    int t = blockIdx.x * blockDim.x + threadIdx.x;
    if (t >= total) return;
    int i    = t & 7;
    int lane = (t >> 3) & 63;
    int blk  = t >> 9;            // nt*4 + ks
    int ks = blk & 3, nt = blk >> 2;
    int np = nt * 16 + (lane & 15);
    int k  = ks * 32 + ((lane >> 4) << 3) + i;
    int g = np / 112, j = np % 112;
    float v = (j < 100 && k < 100) ? W_hh[(g * 100 + j) * 100 + k] : 0.f;
    short hi = f2bf(v);
    short lo = f2bf(v - bf2f(hi));
    Bhi[t] = hi;
    Blo[t] = lo;
}

// ---------------------------------------------------------------------------
// Generic B-fragment pack (same frag layout as k_bpack, zero-padded).
// ---------------------------------------------------------------------------
__global__ void k_pack(const float* __restrict__ W, short* __restrict__ Ph,
                       short* __restrict__ Pl, int K, int J, int ld, int trans,
                       int KS, int total) {
    int t = blockIdx.x * blockDim.x + threadIdx.x;
    if (t >= total) return;
    int i    = t & 7;
    int lane = (t >> 3) & 63;
    int blk  = t >> 9;
    int ks = blk % KS, ct = blk / KS;
    int j = ct * 16 + (lane & 15);
    int k = ks * 32 + ((lane >> 4) << 3) + i;
    float v = 0.f;
    if (j < J && k < K) v = trans ? W[(long)j * ld + k] : W[(long)k * ld + j];
    short hi = f2bf(v);
    Ph[t] = hi;
    Pl[t] = f2bf(v - bf2f(hi));
}

// ---------------------------------------------------------------------------
// Generic MFMA GEMM: out[n, j] = sum_k A[n,k]*B[k,j] (+ bias[j]).
// ileave=1: write in GRU-interleaved layout  off = row*300 + (j%100)*3 + j/100
// (3 gates of one column contiguous -> GRU wx gather becomes one dwordx3).
// ---------------------------------------------------------------------------
template <int KS>
__global__ __launch_bounds__(448) void k_gemm(
        const float* __restrict__ A, int K, int nrows,
        const short* __restrict__ Bh, const short* __restrict__ Bl,
        const float* __restrict__ bias, float* __restrict__ out, int ldo,
        int J, int CT, int ileave) {
    constexpr int Kp  = KS * 32;
    constexpr int STR = Kp + 8;                 // shorts per staged row
    __shared__ short sA[2][64 * STR];           // [hi/lo][row*STR + k]

    const int tid  = threadIdx.x;
    const int w    = tid >> 6;
    const int lane = tid & 63;
    const int n0   = lane & 15;
    const int q    = lane >> 4;
    const int row0 = blockIdx.x * 64;

    for (int idx = tid; idx < 64 * Kp; idx += 448) {
        int nd = idx / Kp, c = idx % Kp;
        int r = row0 + nd; if (r >= nrows) r = nrows - 1;
        float v = (c < K) ? A[(long)r * K + c] : 0.f;
        short hi = f2bf(v);
        sA[0][nd * STR + c] = hi;
        sA[1][nd * STR + c] = f2bf(v - bf2f(hi));
    }
    __syncthreads();

    for (int ct = w; ct < CT; ct += 7) {
        bf16x8 bh[KS], bl[KS];
#pragma unroll
        for (int ks = 0; ks < KS; ++ks) {
            long bo = ((long)(ct * KS + ks) * 64 + lane) * 8;
            bh[ks] = *(const bf16x8*)&Bh[bo];
            bl[ks] = *(const bf16x8*)&Bl[bo];
        }
        const int j = ct * 16 + n0;
        const bool jv = (j < J);
        const float bv = (bias != nullptr && jv) ? bias[j] : 0.f;
        const long obase = ileave ? ((long)(j % 100) * 3 + (j / 100)) : (long)j;

#pragma unroll
        for (int t = 0; t < 4; ++t) {
            f32x4 acc = (f32x4){0.f, 0.f, 0.f, 0.f};
#pragma unroll
            for (int ks = 0; ks < KS; ++ks) {
                int off = (t * 16 + n0) * STR + ks * 32 + q * 8;
                bf16x8 aHi = *(const bf16x8*)&sA[0][off];
                bf16x8 aLo = *(const bf16x8*)&sA[1][off];
                acc = __builtin_amdgcn_mfma_f32_16x16x32_bf16(aHi, bh[ks], acc, 0, 0, 0);
                acc = __builtin_amdgcn_mfma_f32_16x16x32_bf16(aHi, bl[ks], acc, 0, 0, 0);
                acc = __builtin_amdgcn_mfma_f32_16x16x32_bf16(aLo, bh[ks], acc, 0, 0, 0);
            }
            if (jv) {
#pragma unroll
                for (int r = 0; r < 4; ++r) {
                    int row = row0 + t * 16 + 4 * q + r;
                    if (row < nrows) out[(long)row * ldo + obase] = acc[r] + bv;
                }
            }
        }
    }
}

// ---------------------------------------------------------------------------
// Conv2 GEMM with fused concat staging: A row r = relu([xc1[r], hn[idx[r]]]),
// K=200 (Kp=224). Eliminates the xbig materialization (96MB round-trip).
// ---------------------------------------------------------------------------
__global__ __launch_bounds__(448) void k_gemm_cat(
        const float* __restrict__ xc1, const float* __restrict__ hn,
        const int* __restrict__ idx, int nrows,
        const short* __restrict__ Bh, const short* __restrict__ Bl,
        float* __restrict__ out, int CT) {
    constexpr int KS = 7, Kp = 224, STR = 232;
    __shared__ short sA[2][64 * STR];

    const int tid  = threadIdx.x;
    const int w    = tid >> 6;
    const int lane = tid & 63;
    const int n0   = lane & 15;
    const int q    = lane >> 4;
    const int row0 = blockIdx.x * 64;

    for (int t = tid; t < 64 * Kp; t += 448) {
        int nd = t / Kp, c = t % Kp;
        int r = row0 + nd; if (r >= nrows) r = nrows - 1;
        float v = 0.f;
        if (c < 100)      v = fmaxf(xc1[(long)r * 100 + c], 0.f);
        else if (c < 200) v = fmaxf(hn[(long)idx[r] * 100 + (c - 100)], 0.f);
        short hi = f2bf(v);
        sA[0][nd * STR + c] = hi;
        sA[1][nd * STR + c] = f2bf(v - bf2f(hi));
    }
    __syncthreads();

    for (int ct = w; ct < CT; ct += 7) {
        bf16x8 bh[KS], bl[KS];
#pragma unroll
        for (int ks = 0; ks < KS; ++ks) {
            long bo = ((long)(ct * KS + ks) * 64 + lane) * 8;
            bh[ks] = *(const bf16x8*)&Bh[bo];
            bl[ks] = *(const bf16x8*)&Bl[bo];
        }
        const int j = ct * 16 + n0;
        const bool jv = (j < 100);

#pragma unroll
        for (int t4 = 0; t4 < 4; ++t4) {
            f32x4 acc = (f32x4){0.f, 0.f, 0.f, 0.f};
#pragma unroll
            for (int ks = 0; ks < KS; ++ks) {
                int off = (t4 * 16 + n0) * STR + ks * 32 + q * 8;
                bf16x8 aHi = *(const bf16x8*)&sA[0][off];
                bf16x8 aLo = *(const bf16x8*)&sA[1][off];
                acc = __builtin_amdgcn_mfma_f32_16x16x32_bf16(aHi, bh[ks], acc, 0, 0, 0);
                acc = __builtin_amdgcn_mfma_f32_16x16x32_bf16(aHi, bl[ks], acc, 0, 0, 0);
                acc = __builtin_amdgcn_mfma_f32_16x16x32_bf16(aLo, bh[ks], acc, 0, 0, 0);
            }
            if (jv) {
#pragma unroll
                for (int r = 0; r < 4; ++r) {
                    int row = row0 + t4 * 16 + 4 * q + r;
                    if (row < nrows) out[(long)row * 100 + j] = acc[r];
                }
            }
        }
    }
}

// ---------------------------------------------------------------------------
// MFMA GRU, round 9: 7 waves, B hi+lo register-resident, double-buffered h
// tables, ONE barrier/step — now THREE 16-node tiles per block (48 nodes):
// 1250 blocks -> makespan 7.5 tile-units vs 8 (2-tile), and per-step fixed
// lockstep costs amortize /3. wx gathers read interleaved Wemb ([v][jc][g])
// as one dwordx3 per (tile,row) instead of 3 scalar loads.
// ---------------------------------------------------------------------------
__global__ __launch_bounds__(448, 2) void k_gru_mfma(
        const int* __restrict__ tok, const float* __restrict__ h0,
        const float* __restrict__ Wemb, const short* __restrict__ Bhi,
        const short* __restrict__ Blo, const float* __restrict__ b_hh,
        float* __restrict__ hout, int n_nodes) {
    __shared__ short hA[2][2][48 * 136];   // [buf][hi/lo][node*136+k], 52224B

    const int tid  = threadIdx.x;
    const int w    = tid >> 6;
    const int lane = tid & 63;
    const int n0   = lane & 15;
    const int q    = lane >> 4;
    const int node0 = blockIdx.x * 48;

    // ---- B fragments: 3 gates x 4 k-steps, hi+lo, loaded once ----
    bf16x8 bh[3][4], bl[3][4];
#pragma unroll
    for (int g = 0; g < 3; ++g)
#pragma unroll
        for (int ks = 0; ks < 4; ++ks) {
            long bo = ((long)((g * 7 + w) * 4 + ks) * 64 + lane) * 8;
            bh[g][ks] = *(const bf16x8*)&Bhi[bo];
            bl[g][ks] = *(const bf16x8*)&Blo[bo];
        }

    // ---- init h tables; buffer 1 zeroed so its k-pad (100..127) is 0 ----
    for (int i = tid; i < 48 * 128; i += 448) {
        int nd = i >> 7, c = i & 127;
        int row = node0 + nd; if (row >= n_nodes) row = n_nodes - 1;
        float v = (c < 100) ? h0[(long)row * 100 + c] : 0.f;
        short hi = f2bf(v);
        hA[0][0][nd * 136 + c] = hi;
        hA[0][1][nd * 136 + c] = f2bf(v - bf2f(hi));
        hA[1][0][nd * 136 + c] = 0;
        hA[1][1][nd * 136 + c] = 0;
    }

    const int j   = 16 * w + n0;
    const int jc  = j < 100 ? j : 99;
    const bool jok = (j < 100);
    const float bhr = b_hh[jc], bhz = b_hh[100 + jc], bhn = b_hh[200 + jc];

    int rows0[4], rows1[4], rows2[4];
#pragma unroll
    for (int r = 0; r < 4; ++r) {
        int a0 = node0 + 4 * q + r;
        int a1 = a0 + 16;
        int a2 = a0 + 32;
        rows0[r] = a0 < n_nodes ? a0 : n_nodes - 1;
        rows1[r] = a1 < n_nodes ? a1 : n_nodes - 1;
        rows2[r] = a2 < n_nodes ? a2 : n_nodes - 1;
    }
    float hp0[4], hp1[4], hp2[4];
#pragma unroll
    for (int r = 0; r < 4; ++r) hp0[r] = h0[(long)rows0[r] * 100 + jc];
#pragma unroll
    for (int r = 0; r < 4; ++r) hp1[r] = h0[(long)rows1[r] * 100 + jc];
#pragma unroll
    for (int r = 0; r < 4; ++r) hp2[r] = h0[(long)rows2[r] * 100 + jc];

    __syncthreads();

    int tb0[4], tb1[4], tb2[4];
#pragma unroll
    for (int r = 0; r < 4; ++r) tb0[r] = tok[(long)rows0[r] * SEQL] * 300;
#pragma unroll
    for (int r = 0; r < 4; ++r) tb1[r] = tok[(long)rows1[r] * SEQL] * 300;
#pragma unroll
    for (int r = 0; r < 4; ++r) tb2[r] = tok[(long)rows2[r] * SEQL] * 300;

    const int jc3 = 3 * jc;

    int cur = 0;
#pragma unroll 1
    for (int l = 0; l < SEQL; ++l) {
        // wx for tiles 0,1 issued first (consumed at their epilogues)
        float wxA[12], wxB[12];
#pragma unroll
        for (int r = 0; r < 4; ++r) {
            const float* p = Wemb + (long)tb0[r] + jc3;
            wxA[r] = p[0]; wxA[4 + r] = p[1]; wxA[8 + r] = p[2];
        }
#pragma unroll
        for (int r = 0; r < 4; ++r) {
            const float* p = Wemb + (long)tb1[r] + jc3;
            wxB[r] = p[0]; wxB[4 + r] = p[1]; wxB[8 + r] = p[2];
        }

        // next step's token bases
        int tnx[4], tny[4], tnz[4];
        if (l < SEQL - 1) {
#pragma unroll
            for (int r = 0; r < 4; ++r) tnx[r] = tok[(long)rows0[r] * SEQL + l + 1] * 300;
#pragma unroll
            for (int r = 0; r < 4; ++r) tny[r] = tok[(long)rows1[r] * SEQL + l + 1] * 300;
#pragma unroll
            for (int r = 0; r < 4; ++r) tnz[r] = tok[(long)rows2[r] * SEQL + l + 1] * 300;
        }

        const short* hc0 = &hA[cur][0][0];
        const short* hc1 = &hA[cur][1][0];
        short* hn0 = &hA[cur ^ 1][0][0];
        short* hn1 = &hA[cur ^ 1][1][0];

        f32x4 acc[3];
        auto epi = [&](const float* wx, float* hp, int ndo) {
#pragma unroll
            for (int r = 0; r < 4; ++r) {
                float pr = wx[r]     + acc[0][r] + bhr;
                float pz = wx[4 + r] + acc[1][r] + bhz;
                float rr = __builtin_amdgcn_rcpf(1.f + __expf(-pr));
                float zz = __builtin_amdgcn_rcpf(1.f + __expf(-pz));
                float pn = wx[8 + r] + rr * (acc[2][r] + bhn);
                float th = 1.f - 2.f * __builtin_amdgcn_rcpf(1.f + __expf(2.f * pn));
                float hnew = (1.f - zz) * th + zz * hp[r];
                hp[r] = hnew;
                if (jok) {
                    int off = (ndo + 4 * q + r) * 136 + j;
                    short hi = f2bf(hnew);
                    hn0[off] = hi;
                    hn1[off] = f2bf(hnew - bf2f(hi));
                }
            }
        };

        // ---- tile 0 ----
        {
            bf16x8 aHi[4], aLo[4];
#pragma unroll
            for (int ks = 0; ks < 4; ++ks) {
                int off = n0 * 136 + ks * 32 + q * 8;
                aHi[ks] = *(const bf16x8*)&hc0[off];
                aLo[ks] = *(const bf16x8*)&hc1[off];
            }
#pragma unroll
            for (int g = 0; g < 3; ++g) acc[g] = (f32x4){0.f, 0.f, 0.f, 0.f};
#pragma unroll
            for (int g = 0; g < 3; ++g)
#pragma unroll
                for (int ks = 0; ks < 4; ++ks) {
                    acc[g] = __builtin_amdgcn_mfma_f32_16x16x32_bf16(aHi[ks], bh[g][ks], acc[g], 0, 0, 0);
                    acc[g] = __builtin_amdgcn_mfma_f32_16x16x32_bf16(aHi[ks], bl[g][ks], acc[g], 0, 0, 0);
                    acc[g] = __builtin_amdgcn_mfma_f32_16x16x32_bf16(aLo[ks], bh[g][ks], acc[g], 0, 0, 0);
                }
            epi(wxA, hp0, 0);
        }

        // wx for tile 2 (covered by tile-1 MFMAs)
        float wxC[12];
#pragma unroll
        for (int r = 0; r < 4; ++r) {
            const float* p = Wemb + (long)tb2[r] + jc3;
            wxC[r] = p[0]; wxC[4 + r] = p[1]; wxC[8 + r] = p[2];
        }

        // ---- tile 1 ----
        {
            bf16x8 aHi[4], aLo[4];
#pragma unroll
            for (int ks = 0; ks < 4; ++ks) {
                int off = (16 + n0) * 136 + ks * 32 + q * 8;
                aHi[ks] = *(const bf16x8*)&hc0[off];
                aLo[ks] = *(const bf16x8*)&hc1[off];
            }
#pragma unroll
            for (int g = 0; g < 3; ++g) acc[g] = (f32x4){0.f, 0.f, 0.f, 0.f};
#pragma unroll
            for (int g = 0; g < 3; ++g)
#pragma unroll
                for (int ks = 0; ks < 4; ++ks) {
                    acc[g] = __builtin_amdgcn_mfma_f32_16x16x32_bf16(aHi[ks], bh[g][ks], acc[g], 0, 0, 0);
                    acc[g] = __builtin_amdgcn_mfma_f32_16x16x32_bf16(aHi[ks], bl[g][ks], acc[g], 0, 0, 0);
                    acc[g] = __builtin_amdgcn_mfma_f32_16x16x32_bf16(aLo[ks], bh[g][ks], acc[g], 0, 0, 0);
                }
            epi(wxB, hp1, 16);
        }

        // ---- tile 2 ----
        {
            bf16x8 aHi[4], aLo[4];
#pragma unroll
            for (int ks = 0; ks < 4; ++ks) {
                int off = (32 + n0) * 136 + ks * 32 + q * 8;
                aHi[ks] = *(const bf16x8*)&hc0[off];
                aLo[ks] = *(const bf16x8*)&hc1[off];
            }
#pragma unroll
            for (int g = 0; g < 3; ++g) acc[g] = (f32x4){0.f, 0.f, 0.f, 0.f};
#pragma unroll
            for (int g = 0; g < 3; ++g)
#pragma unroll
                for (int ks = 0; ks < 4; ++ks) {
                    acc[g] = __builtin_amdgcn_mfma_f32_16x16x32_bf16(aHi[ks], bh[g][ks], acc[g], 0, 0, 0);
                    acc[g] = __builtin_amdgcn_mfma_f32_16x16x32_bf16(aHi[ks], bl[g][ks], acc[g], 0, 0, 0);
                    acc[g] = __builtin_amdgcn_mfma_f32_16x16x32_bf16(aLo[ks], bh[g][ks], acc[g], 0, 0, 0);
                }
            epi(wxC, hp2, 32);
        }

        if (l < SEQL - 1) {
#pragma unroll
            for (int r = 0; r < 4; ++r) { tb0[r] = tnx[r]; tb1[r] = tny[r]; tb2[r] = tnz[r]; }
        }
        __syncthreads();
        cur ^= 1;
    }

    for (int i = tid; i < 48 * 100; i += 448) {
        int nd = i / 100, c = i % 100;
        if (node0 + nd < n_nodes)
            hout[(long)(node0 + nd) * 100 + c] =
                bf2f(hA[cur][0][nd * 136 + c]) + bf2f(hA[cur][1][nd * 136 + c]);
    }
}

// ---------------------------------------------------------------------------
// Degree (int atomics)
// ---------------------------------------------------------------------------
__global__ void k_deg(const int* __restrict__ dst, int* __restrict__ degi, int E) {
    int e = blockIdx.x * blockDim.x + threadIdx.x;
    if (e < E) atomicAdd(&degi[dst[e]], 1);
}

// ---------------------------------------------------------------------------
// Parallel scan (replaces the single-block k_scan which serialized on 1 CU):
// per-block sums -> exclusive scan of partials -> emit rs/cursor/dinv.
// ---------------------------------------------------------------------------
__global__ __launch_bounds__(256) void k_scan_bsum(const int* __restrict__ degi,
                                                   int* __restrict__ bsum, int N) {
    __shared__ int sh[256];
    int t = threadIdx.x, i = blockIdx.x * 256 + t;
    sh[t] = (i < N) ? degi[i] : 0;
    __syncthreads();
    for (int o = 128; o > 0; o >>= 1) {
        if (t < o) sh[t] += sh[t + o];
        __syncthreads();
    }
    if (t == 0) bsum[blockIdx.x] = sh[0];
}

__global__ __launch_bounds__(1024) void k_scan_part(int* __restrict__ bsum, int G) {
    __shared__ int sh[1024];
    int t = threadIdx.x;
    int v = (t < G) ? bsum[t] : 0;
    sh[t] = v;
    __syncthreads();
    for (int o = 1; o < 1024; o <<= 1) {
        int a = (t >= o) ? sh[t - o] : 0;
        __syncthreads();
        sh[t] += a;
        __syncthreads();
    }
    if (t < G) bsum[t] = sh[t] - v;   // exclusive
}

__global__ __launch_bounds__(256) void k_scan_emit(const int* __restrict__ degi,
                                                   const int* __restrict__ bsum,
                                                   int* __restrict__ rs, int* __restrict__ cursor,
                                                   float* __restrict__ dinv, int N, int E) {
    __shared__ int sh[256];
    int t = threadIdx.x, i = blockIdx.x * 256 + t;
    int d = (i < N) ? degi[i] : 0;
    sh[t] = d;
    __syncthreads();
    for (int o = 1; o < 256; o <<= 1) {
        int a = (t >= o) ? sh[t - o] : 0;
        __syncthreads();
        sh[t] += a;
        __syncthreads();
    }
    if (i < N) {
        int run = bsum[blockIdx.x] + sh[t] - d;
        rs[i] = run;
        cursor[i] = run;
        dinv[i] = rsqrtf((float)d + 1.0f);
        if (i == N - 1) rs[N] = E;
    }
}

// ---------------------------------------------------------------------------
// Scatter edges into CSR order (by dst)
// ---------------------------------------------------------------------------
__global__ void k_scatter(const int* __restrict__ src, const int* __restrict__ dst,
                          int* __restrict__ cursor, int* __restrict__ esrc, int E) {
    int e = blockIdx.x * blockDim.x + threadIdx.x;
    if (e >= E) return;
    int pos = atomicAdd(&cursor[dst[e]], 1);
    esrc[pos] = src[e];
}

// ---------------------------------------------------------------------------
// Conv1 finish: CSR gather (no atomics) + self term + bias -> xc1 (pre-relu).
// (xbig no longer materialized; conv2's GEMM stages the concat directly.)
// ---------------------------------------------------------------------------
__global__ void k_conv1_fin(const int* __restrict__ rs, const int* __restrict__ esrc,
                            const float* __restrict__ xw, const float* __restrict__ dinv,
                            const float* __restrict__ b1, float* __restrict__ xc1, int N) {
    int t = blockIdx.x * blockDim.x + threadIdx.x;
    if (t >= N * 25) return;
    int n = t / 25, jq = t % 25;
    float dn = dinv[n];
    float4 acc = {0.f, 0.f, 0.f, 0.f};
    int e1 = rs[n + 1];
    for (int e = rs[n]; e < e1; ++e) {
        int s = esrc[e];
        float ds = dinv[s];
        float4 xs = ((const float4*)xw)[s * 25 + jq];
        acc.x = fmaf(xs.x, ds, acc.x);
        acc.y = fmaf(xs.y, ds, acc.y);
        acc.z = fmaf(xs.z, ds, acc.z);
        acc.w = fmaf(xs.w, ds, acc.w);
    }
    float4 xs = ((const float4*)xw)[t];
    float4 bq = ((const float4*)b1)[jq];
    float dn2 = dn * dn;
    float4 v;
    v.x = fmaf(acc.x, dn, fmaf(xs.x, dn2, bq.x));
    v.y = fmaf(acc.y, dn, fmaf(xs.y, dn2, bq.y));
    v.z = fmaf(acc.z, dn, fmaf(xs.z, dn2, bq.z));
    v.w = fmaf(acc.w, dn, fmaf(xs.w, dn2, bq.w));
    ((float4*)xc1)[t] = v;
}

// ---------------------------------------------------------------------------
// Conv2 finish: out = [relu(agg2 + self + b2), xc1[idx]]
// ---------------------------------------------------------------------------
__global__ void k_conv2_fin(const int* __restrict__ rs, const int* __restrict__ esrc,
                            const float* __restrict__ xw, const float* __restrict__ dinv,
                            const float* __restrict__ b2, const float* __restrict__ xc1,
                            const int* __restrict__ idx, float* __restrict__ out, int N) {
    int t = blockIdx.x * blockDim.x + threadIdx.x;
    if (t >= N * 25) return;
    int n = t / 25, jq = t % 25;
    float dn = dinv[n];
    float4 acc = {0.f, 0.f, 0.f, 0.f};
    int e1 = rs[n + 1];
    for (int e = rs[n]; e < e1; ++e) {
        int s = esrc[e];
        float ds = dinv[s];
        float4 xs = ((const float4*)xw)[s * 25 + jq];
        acc.x = fmaf(xs.x, ds, acc.x);
        acc.y = fmaf(xs.y, ds, acc.y);
        acc.z = fmaf(xs.z, ds, acc.z);
        acc.w = fmaf(xs.w, ds, acc.w);
    }
    float4 xs = ((const float4*)xw)[t];
    float4 bq = ((const float4*)b2)[jq];
    float dn2 = dn * dn;
    float4 v;
    v.x = fmaxf(fmaf(acc.x, dn, fmaf(xs.x, dn2, bq.x)), 0.f);
    v.y = fmaxf(fmaf(acc.y, dn, fmaf(xs.y, dn2, bq.y)), 0.f);
    v.z = fmaxf(fmaf(acc.z, dn, fmaf(xs.z, dn2, bq.z)), 0.f);
    v.w = fmaxf(fmaf(acc.w, dn, fmaf(xs.w, dn2, bq.w)), 0.f);
    float4 rv = ((const float4*)xc1)[(long)idx[n] * 25 + jq];
    ((float4*)out)[n * 50 + jq] = v;
    ((float4*)out)[n * 50 + 25 + jq] = rv;
}

// ---------------------------------------------------------------------------
extern "C" void kernel_launch(void* const* d_in, const int* in_sizes, int n_in,
                              void* d_out, int out_size, void* d_ws, size_t ws_size,
                              hipStream_t stream) {
    const int*   feat    = (const int*)d_in[0];
    const int*   edges   = (const int*)d_in[1];
    const int*   indices = (const int*)d_in[2];
    const float* h0      = (const float*)d_in[3];
    const float* emb     = (const float*)d_in[4];
    const float* W_ih    = (const float*)d_in[5];
    const float* W_hh    = (const float*)d_in[6];
    const float* b_ih    = (const float*)d_in[7];
    const float* b_hh    = (const float*)d_in[8];
    const float* W1      = (const float*)d_in[9];
    const float* b1      = (const float*)d_in[10];
    const float* W2      = (const float*)d_in[11];
    const float* b2      = (const float*)d_in[12];
    float* out = (float*)d_out;

    const int N = in_sizes[2];
    const int E = in_sizes[1] / 2;
    const int V = in_sizes[4] / D_IN;
    const int* src = edges;
    const int* dst = edges + E;

    float* ws   = (float*)d_ws;
    float* hbuf = ws;                         // N*100
    float* Wemb = hbuf + (long)N * H;         // V*300 (reused as xw after GRU)
    float* xw   = Wemb;                       // reuse: N*100
    float* xc1  = Wemb + (long)V * 300;       // N*100
    float* xbig = xc1 + (long)N * 100;        // N*200 (unused; kept for layout)
    float* dinv = xbig + (long)N * 200;       // N
    short* Bhi  = (short*)(dinv + N);         // 43008 bf16 (GRU W_hh)
    short* Blo  = Bhi + 43008;                // 43008
    short* PihH = Blo + 43008;                // 38912 (W_ih: CT=19, KS=4)
    short* PihL = PihH + 38912;               // 38912
    short* P1H  = PihL + 38912;               // 14336 (W1: CT=7, KS=4)
    short* P1L  = P1H + 14336;                // 14336
    short* P2H  = P1L + 14336;                // 25088 (W2: CT=7, KS=7)
    short* P2L  = P2H + 25088;                // 25088
    int*   degi = (int*)(P2L + 25088);        // N
    int*   rs   = degi + N;                   // N+1
    int*   cursor = rs + N + 1;               // N
    int*   esrc = cursor + N;                 // E
    int*   bsum = esrc + E;                   // ceil(N/256) partials
    (void)ws_size; (void)n_in; (void)out_size;

    const int B = 256;
    const int Gs = (N + 255) / 256;

    hipMemsetAsync(degi, 0, (size_t)N * sizeof(int), stream);
    k_deg<<<(E + B - 1) / B, B, 0, stream>>>(dst, degi, E);
    k_scan_bsum<<<Gs, 256, 0, stream>>>(degi, bsum, N);
    k_scan_part<<<1, 1024, 0, stream>>>(bsum, Gs);
    k_scan_emit<<<Gs, 256, 0, stream>>>(degi, bsum, rs, cursor, dinv, N, E);
    k_scatter<<<(E + B - 1) / B, B, 0, stream>>>(src, dst, cursor, esrc, E);

    k_bpack<<<(43008 + B - 1) / B, B, 0, stream>>>(W_hh, Bhi, Blo, 43008);
    k_pack<<<(38912 + B - 1) / B, B, 0, stream>>>(W_ih, PihH, PihL, 100, 300, 100, 1, 4, 38912);
    k_pack<<<(14336 + B - 1) / B, B, 0, stream>>>(W1, P1H, P1L, 100, 100, 100, 0, 4, 14336);
    k_pack<<<(25088 + B - 1) / B, B, 0, stream>>>(W2, P2H, P2L, 200, 100, 100, 0, 7, 25088);

    // Wemb = emb @ W_ih^T + b_ih, interleaved [v][jc][g]
    k_gemm<4><<<(V + 63) / 64, 448, 0, stream>>>(emb, 100, V, PihH, PihL, b_ih,
                                                 Wemb, 300, 300, 19, 1);

    k_gru_mfma<<<(N + 47) / 48, 448, 0, stream>>>(feat, h0, Wemb, Bhi, Blo, b_hh, hbuf, N);

    {
        // xw = hbuf @ W1
        k_gemm<4><<<(N + 63) / 64, 448, 0, stream>>>(hbuf, 100, N, P1H, P1L, nullptr,
                                                     xw, 100, 100, 7, 0);
        int nquads = N * 25;
        k_conv1_fin<<<(nquads + B - 1) / B, B, 0, stream>>>(rs, esrc, xw, dinv, b1, xc1, N);
        // xw = relu([xc1, hn[idx]]) @ W2  (concat staged in-kernel)
        k_gemm_cat<<<(N + 63) / 64, 448, 0, stream>>>(xc1, hbuf, indices, N,
                                                      P2H, P2L, xw, 7);
        k_conv2_fin<<<(nquads + B - 1) / B, B, 0, stream>>>(rs, esrc, xw, dinv, b2, xc1,
                                                            indices, out, N);
    }
}